// Round 1
// baseline (2355.680 us; speedup 1.0000x reference)
//
#include <hip/hip_runtime.h>
#include <math.h>

// ---------------- wave helpers ----------------
__device__ __forceinline__ float wave_reduce_sum(float v) {
  #pragma unroll
  for (int off = 32; off > 0; off >>= 1) v += __shfl_xor(v, off, 64);
  return v;
}
__device__ __forceinline__ float wave_reduce_max(float v) {
  #pragma unroll
  for (int off = 32; off > 0; off >>= 1) v = fmaxf(v, __shfl_xor(v, off, 64));
  return v;
}

// ---------------- setup kernels ----------------
__global__ void k_init(int* cnt, int* meta, int N) {
  int i = blockIdx.x * blockDim.x + threadIdx.x;
  if (i < N) cnt[i] = 0;
  if (i < 32) meta[i] = 0;
}

__global__ void k_count(const int* __restrict__ col, int* __restrict__ cnt, int E) {
  int e = blockIdx.x * blockDim.x + threadIdx.x;
  if (e < E) atomicAdd(&cnt[col[e]], 1);
}

// block scans 1024 elements (256 threads x 4), writes inclusive scan + block sum
__global__ __launch_bounds__(256) void k_scanA(const int* __restrict__ cnt,
                                               int* __restrict__ incl,
                                               int* __restrict__ bsums, int N) {
  __shared__ int s[1024];
  int base = blockIdx.x * 1024;
  #pragma unroll
  for (int t = 0; t < 4; ++t) {
    int i = threadIdx.x + t * 256;
    int idx = base + i;
    s[i] = (idx < N) ? cnt[idx] : 0;
  }
  __syncthreads();
  for (int d = 1; d < 1024; d <<= 1) {
    int v[4];
    #pragma unroll
    for (int t = 0; t < 4; ++t) {
      int i = threadIdx.x + t * 256;
      v[t] = (i >= d) ? s[i - d] : 0;
    }
    __syncthreads();
    #pragma unroll
    for (int t = 0; t < 4; ++t) {
      int i = threadIdx.x + t * 256;
      s[i] += v[t];
    }
    __syncthreads();
  }
  #pragma unroll
  for (int t = 0; t < 4; ++t) {
    int i = threadIdx.x + t * 256;
    int idx = base + i;
    if (idx < N) incl[idx] = s[i];
  }
  if (threadIdx.x == 0) bsums[blockIdx.x] = s[1023];
}

// single block: exclusive scan of block sums (nb <= 1024)
__global__ __launch_bounds__(256) void k_scanB(const int* __restrict__ bsums,
                                               int* __restrict__ boff, int nb) {
  __shared__ int s[1024];
  #pragma unroll
  for (int t = 0; t < 4; ++t) {
    int i = threadIdx.x + t * 256;
    s[i] = (i < nb) ? bsums[i] : 0;
  }
  __syncthreads();
  for (int d = 1; d < 1024; d <<= 1) {
    int v[4];
    #pragma unroll
    for (int t = 0; t < 4; ++t) {
      int i = threadIdx.x + t * 256;
      v[t] = (i >= d) ? s[i - d] : 0;
    }
    __syncthreads();
    #pragma unroll
    for (int t = 0; t < 4; ++t) {
      int i = threadIdx.x + t * 256;
      s[i] += v[t];
    }
    __syncthreads();
  }
  #pragma unroll
  for (int t = 0; t < 4; ++t) {
    int i = threadIdx.x + t * 256;
    if (i < nb) boff[i] = (i == 0) ? 0 : s[i - 1];
  }
}

// finalize: exclusive rowptr, cursor copy, dinv. incl may alias rowptr (read own idx then write own idx).
__global__ void k_scanC(const int* __restrict__ cnt, const int* __restrict__ incl,
                        const int* __restrict__ boff, int* __restrict__ rowptr,
                        int* __restrict__ cursor, float* __restrict__ dinv, int N, int E) {
  int i = blockIdx.x * blockDim.x + threadIdx.x;
  if (i < N) {
    int ex = incl[i] - cnt[i] + boff[i >> 10];
    rowptr[i] = ex;
    cursor[i] = ex;
    dinv[i] = rsqrtf((float)(cnt[i] + 1));  // +1 self loop, always > 0
    if (i == 0) rowptr[N] = E;
  }
}

__global__ void k_scatter(const int* __restrict__ row, const int* __restrict__ col,
                          int* __restrict__ cursor, int* __restrict__ csr, int E) {
  int e = blockIdx.x * blockDim.x + threadIdx.x;
  if (e < E) {
    int c = col[e];
    int p = atomicAdd(&cursor[c], 1);
    csr[p] = row[e];
  }
}

// ---------------- gating: one wave per node, fp32 exact-ish argmax ----------------
__global__ __launch_bounds__(256) void k_gate(const float* __restrict__ x,
                                              const float* __restrict__ wg,
                                              int* __restrict__ eidx,
                                              int* __restrict__ meta, int N) {
  int wid = (blockIdx.x * blockDim.x + threadIdx.x) >> 6;
  int lane = threadIdx.x & 63;
  if (wid >= N) return;
  const float* xr = x + (size_t)wid * 512;
  float l0 = 0.f, l1 = 0.f, l2 = 0.f, l3 = 0.f;
  #pragma unroll
  for (int i = 0; i < 8; ++i) {
    int k = lane + 64 * i;
    float xv = xr[k];
    float4 w = *(const float4*)(wg + 4 * k);
    l0 += xv * w.x; l1 += xv * w.y; l2 += xv * w.z; l3 += xv * w.w;
  }
  l0 = wave_reduce_sum(l0);
  l1 = wave_reduce_sum(l1);
  l2 = wave_reduce_sum(l2);
  l3 = wave_reduce_sum(l3);
  if (lane == 0) {
    int a = 0; float best = l0;
    if (l1 > best) { best = l1; a = 1; }
    if (l2 > best) { best = l2; a = 2; }
    if (l3 > best) { best = l3; a = 3; }
    eidx[wid] = a;
    atomicAdd(&meta[a], 1);
  }
}

// meta layout: [0..3] hist, [4..8] eoff, [9..13] toff, [14..17] ecur
__global__ void k_offs(int* meta) {
  if (threadIdx.x == 0 && blockIdx.x == 0) {
    int* hist = meta;
    int* eoff = meta + 4;
    int* toff = meta + 9;
    int* ecur = meta + 14;
    int s = 0, t = 0;
    eoff[0] = 0; toff[0] = 0;
    for (int e = 0; e < 4; ++e) {
      s += hist[e];
      eoff[e + 1] = s;
      t += (hist[e] + 63) / 64;
      toff[e + 1] = t;
      ecur[e] = eoff[e];
    }
  }
}

__global__ void k_binscatter(const int* __restrict__ eidx, int* __restrict__ meta,
                             int* __restrict__ perm, int N) {
  int n = blockIdx.x * blockDim.x + threadIdx.x;
  if (n < N) {
    int e = eidx[n];
    int p = atomicAdd(&meta[14 + e], 1);
    perm[p] = n;
  }
}

// ---------------- expert GEMM: gathered rows, tiled 64x64x16 fp32 ----------------
__global__ __launch_bounds__(256) void k_gemm1(const float* __restrict__ x,
                                               const float* __restrict__ ew,
                                               const float* __restrict__ eb,
                                               const int* __restrict__ perm,
                                               const int* __restrict__ meta,
                                               float* __restrict__ h1, int N) {
  __shared__ float As[16][68];
  __shared__ float Bs[16][68];
  const int* eoff = meta + 4;
  const int* toff = meta + 9;
  int v = blockIdx.x;
  if (v >= toff[4]) return;
  int e = 0;
  while (v >= toff[e + 1]) ++e;
  int lt = v - toff[e];
  int m0 = eoff[e] + lt * 64;
  int mEnd = eoff[e + 1];
  int n0 = blockIdx.y * 64;
  int tid = threadIdx.x;

  int a_m = tid >> 2;           // 0..63
  int a_k = (tid & 3) * 4;      // 0,4,8,12
  int gm = m0 + a_m;
  int grow = (gm < mEnd) ? perm[gm] : -1;
  const float* arow = (grow >= 0) ? (x + (size_t)grow * 512) : x;

  int b_k = tid >> 4;           // 0..15
  int b_n = (tid & 15) * 4;     // 0..60
  const float* wbase = ew + (size_t)e * 512 * 256 + (size_t)n0 + b_n;

  int tm = (tid >> 4) * 4;
  int tn = (tid & 15) * 4;
  float acc[4][4] = {};

  for (int k0 = 0; k0 < 512; k0 += 16) {
    float4 av = make_float4(0.f, 0.f, 0.f, 0.f);
    if (grow >= 0) av = *(const float4*)(arow + k0 + a_k);
    As[a_k + 0][a_m] = av.x;
    As[a_k + 1][a_m] = av.y;
    As[a_k + 2][a_m] = av.z;
    As[a_k + 3][a_m] = av.w;
    float4 bv = *(const float4*)(wbase + (size_t)(k0 + b_k) * 256);
    *(float4*)&Bs[b_k][b_n] = bv;
    __syncthreads();
    #pragma unroll
    for (int k = 0; k < 16; ++k) {
      float4 a = *(float4*)&As[k][tm];
      float4 b = *(float4*)&Bs[k][tn];
      acc[0][0] += a.x * b.x; acc[0][1] += a.x * b.y; acc[0][2] += a.x * b.z; acc[0][3] += a.x * b.w;
      acc[1][0] += a.y * b.x; acc[1][1] += a.y * b.y; acc[1][2] += a.y * b.z; acc[1][3] += a.y * b.w;
      acc[2][0] += a.z * b.x; acc[2][1] += a.z * b.y; acc[2][2] += a.z * b.z; acc[2][3] += a.z * b.w;
      acc[3][0] += a.w * b.x; acc[3][1] += a.w * b.y; acc[3][2] += a.w * b.z; acc[3][3] += a.w * b.w;
    }
    __syncthreads();
  }

  #pragma unroll
  for (int i = 0; i < 4; ++i) {
    int m = m0 + tm + i;
    if (m < mEnd) {
      int g = perm[m];
      float4 bb = *(const float4*)(eb + (size_t)e * 256 + n0 + tn);
      float4 o = make_float4(acc[i][0] + bb.x, acc[i][1] + bb.y,
                             acc[i][2] + bb.z, acc[i][3] + bb.w);
      *(float4*)(h1 + (size_t)g * 256 + n0 + tn) = o;
    }
  }
}

// ---------------- propagate 1 (256 features): wave per destination ----------------
__global__ __launch_bounds__(256) void k_prop1(const float* __restrict__ h1,
                                               const int* __restrict__ rowptr,
                                               const int* __restrict__ csr,
                                               const float* __restrict__ dinv,
                                               const float* __restrict__ bias1,
                                               float* __restrict__ hrelu, int N) {
  int c = blockIdx.x * 4 + (threadIdx.x >> 6);
  int lane = threadIdx.x & 63;
  if (c >= N) return;
  float dc = dinv[c];
  const float4* hr = (const float4*)h1;
  float4 acc = hr[(size_t)c * 64 + lane];
  float sl = dc * dc;
  acc.x *= sl; acc.y *= sl; acc.z *= sl; acc.w *= sl;
  int jb = rowptr[c], je = rowptr[c + 1];
  for (int j = jb; j < je; ++j) {
    int r = csr[j];
    float s = dinv[r] * dc;
    float4 hv = hr[(size_t)r * 64 + lane];
    acc.x += hv.x * s; acc.y += hv.y * s; acc.z += hv.z * s; acc.w += hv.w * s;
  }
  float4 b = ((const float4*)bias1)[lane];
  acc.x = fmaxf(acc.x + b.x, 0.f);
  acc.y = fmaxf(acc.y + b.y, 0.f);
  acc.z = fmaxf(acc.z + b.z, 0.f);
  acc.w = fmaxf(acc.w + b.w, 0.f);
  ((float4*)hrelu)[(size_t)c * 64 + lane] = acc;
}

// ---------------- GEMM2: [N,256] x [256,64], tiled 64x64x16 fp32 ----------------
__global__ __launch_bounds__(256) void k_gemm2(const float* __restrict__ A,
                                               const float* __restrict__ B,
                                               float* __restrict__ C, int N) {
  __shared__ float As[16][68];
  __shared__ float Bs[16][68];
  int m0 = blockIdx.x * 64;
  int tid = threadIdx.x;
  int a_m = tid >> 2, a_k = (tid & 3) * 4;
  int b_k = tid >> 4, b_n = (tid & 15) * 4;
  int tm = (tid >> 4) * 4, tn = (tid & 15) * 4;
  int gm = m0 + a_m;
  const float* arow = A + (size_t)gm * 256;
  float acc[4][4] = {};

  for (int k0 = 0; k0 < 256; k0 += 16) {
    float4 av = make_float4(0.f, 0.f, 0.f, 0.f);
    if (gm < N) av = *(const float4*)(arow + k0 + a_k);
    As[a_k + 0][a_m] = av.x;
    As[a_k + 1][a_m] = av.y;
    As[a_k + 2][a_m] = av.z;
    As[a_k + 3][a_m] = av.w;
    float4 bv = *(const float4*)(B + (size_t)(k0 + b_k) * 64 + b_n);
    *(float4*)&Bs[b_k][b_n] = bv;
    __syncthreads();
    #pragma unroll
    for (int k = 0; k < 16; ++k) {
      float4 a = *(float4*)&As[k][tm];
      float4 b = *(float4*)&Bs[k][tn];
      acc[0][0] += a.x * b.x; acc[0][1] += a.x * b.y; acc[0][2] += a.x * b.z; acc[0][3] += a.x * b.w;
      acc[1][0] += a.y * b.x; acc[1][1] += a.y * b.y; acc[1][2] += a.y * b.z; acc[1][3] += a.y * b.w;
      acc[2][0] += a.z * b.x; acc[2][1] += a.z * b.y; acc[2][2] += a.z * b.z; acc[2][3] += a.z * b.w;
      acc[3][0] += a.w * b.x; acc[3][1] += a.w * b.y; acc[3][2] += a.w * b.z; acc[3][3] += a.w * b.w;
    }
    __syncthreads();
  }

  #pragma unroll
  for (int i = 0; i < 4; ++i) {
    int m = m0 + tm + i;
    if (m < N) {
      float4 o = make_float4(acc[i][0], acc[i][1], acc[i][2], acc[i][3]);
      *(float4*)(C + (size_t)m * 64 + tn) = o;
    }
  }
}

// ---------------- propagate 2 (64 features) + bias2 + log_softmax ----------------
__global__ __launch_bounds__(256) void k_prop2(const float* __restrict__ h3,
                                               const int* __restrict__ rowptr,
                                               const int* __restrict__ csr,
                                               const float* __restrict__ dinv,
                                               const float* __restrict__ bias2,
                                               float* __restrict__ out, int N) {
  int c = blockIdx.x * 4 + (threadIdx.x >> 6);
  int f = threadIdx.x & 63;
  if (c >= N) return;
  float dc = dinv[c];
  float acc = h3[(size_t)c * 64 + f] * dc * dc;
  int jb = rowptr[c], je = rowptr[c + 1];
  for (int j = jb; j < je; ++j) {
    int r = csr[j];
    acc += h3[(size_t)r * 64 + f] * (dinv[r] * dc);
  }
  acc += bias2[f];
  float m = wave_reduce_max(acc);
  float ex = expf(acc - m);
  float s = wave_reduce_sum(ex);
  out[(size_t)c * 64 + f] = acc - m - logf(s);
}

// ---------------- launch ----------------
extern "C" void kernel_launch(void* const* d_in, const int* in_sizes, int n_in,
                              void* d_out, int out_size, void* d_ws, size_t ws_size,
                              hipStream_t stream) {
  const float* x  = (const float*)d_in[0];
  const int*   ei = (const int*)d_in[1];
  const float* wg = (const float*)d_in[2];
  const float* ew = (const float*)d_in[3];
  const float* eb = (const float*)d_in[4];
  const float* b1 = (const float*)d_in[5];
  const float* w2 = (const float*)d_in[6];
  const float* b2 = (const float*)d_in[7];
  float* out = (float*)d_out;

  int N = in_sizes[0] / 512;
  int E = in_sizes[1] / 2;
  const int* row = ei;
  const int* col = ei + E;

  char* p = (char*)d_ws;
  auto alloc = [&](size_t bytes) -> void* {
    void* r = (void*)p;
    p += (bytes + 255) & ~(size_t)255;
    return r;
  };
  int*   cnt    = (int*)alloc((size_t)N * 4);
  int*   rowptr = (int*)alloc((size_t)(N + 1) * 4);
  int*   cursor = (int*)alloc((size_t)N * 4);
  int*   bsums  = (int*)alloc(1024 * 4);
  int*   boff   = (int*)alloc(1024 * 4);
  float* dinv   = (float*)alloc((size_t)N * 4);
  int*   eidx   = (int*)alloc((size_t)N * 4);
  int*   meta   = (int*)alloc(32 * 4);
  int*   perm   = (int*)alloc((size_t)N * 4);
  int*   csr    = (int*)alloc((size_t)E * 4);
  float* h1     = (float*)alloc((size_t)N * 256 * 4);
  float* hrelu  = (float*)alloc((size_t)N * 256 * 4);
  float* h3     = (float*)alloc((size_t)N * 64 * 4);

  int nb = (N + 1023) / 1024;

  k_init<<<(N + 255) / 256, 256, 0, stream>>>(cnt, meta, N);
  k_count<<<(E + 255) / 256, 256, 0, stream>>>(col, cnt, E);
  k_scanA<<<nb, 256, 0, stream>>>(cnt, rowptr, bsums, N);
  k_scanB<<<1, 256, 0, stream>>>(bsums, boff, nb);
  k_scanC<<<(N + 255) / 256, 256, 0, stream>>>(cnt, rowptr, boff, rowptr, cursor, dinv, N, E);
  k_scatter<<<(E + 255) / 256, 256, 0, stream>>>(row, col, cursor, csr, E);
  k_gate<<<(N + 3) / 4, 256, 0, stream>>>(x, wg, eidx, meta, N);
  k_offs<<<1, 64, 0, stream>>>(meta);
  k_binscatter<<<(N + 255) / 256, 256, 0, stream>>>(eidx, meta, perm, N);
  dim3 g1((N + 63) / 64 + 4, 4);
  k_gemm1<<<g1, 256, 0, stream>>>(x, ew, eb, perm, meta, h1, N);
  k_prop1<<<(N + 3) / 4, 256, 0, stream>>>(h1, rowptr, csr, dinv, b1, hrelu, N);
  k_gemm2<<<(N + 63) / 64, 256, 0, stream>>>(hrelu, w2, h3, N);
  k_prop2<<<(N + 3) / 4, 256, 0, stream>>>(h3, rowptr, csr, dinv, b2, out, N);
}

// Round 2
// 1089.395 us; speedup vs baseline: 2.1624x; 2.1624x over previous
//
#include <hip/hip_runtime.h>
#include <math.h>

// ---------------- wave helpers ----------------
__device__ __forceinline__ float wave_reduce_sum(float v) {
  #pragma unroll
  for (int off = 32; off > 0; off >>= 1) v += __shfl_xor(v, off, 64);
  return v;
}
__device__ __forceinline__ float wave_reduce_max(float v) {
  #pragma unroll
  for (int off = 32; off > 0; off >>= 1) v = fmaxf(v, __shfl_xor(v, off, 64));
  return v;
}

// ---------------- setup kernels ----------------
__global__ void k_init(int* cnt, int* meta, int N) {
  int i = blockIdx.x * blockDim.x + threadIdx.x;
  if (i < N) cnt[i] = 0;
  if (i < 32) meta[i] = 0;
}

__global__ void k_count(const int* __restrict__ col, int* __restrict__ cnt, int E) {
  int e = blockIdx.x * blockDim.x + threadIdx.x;
  if (e < E) atomicAdd(&cnt[col[e]], 1);
}

// block scans 1024 elements (256 threads x 4), writes inclusive scan + block sum
__global__ __launch_bounds__(256) void k_scanA(const int* __restrict__ cnt,
                                               int* __restrict__ incl,
                                               int* __restrict__ bsums, int N) {
  __shared__ int s[1024];
  int base = blockIdx.x * 1024;
  #pragma unroll
  for (int t = 0; t < 4; ++t) {
    int i = threadIdx.x + t * 256;
    int idx = base + i;
    s[i] = (idx < N) ? cnt[idx] : 0;
  }
  __syncthreads();
  for (int d = 1; d < 1024; d <<= 1) {
    int v[4];
    #pragma unroll
    for (int t = 0; t < 4; ++t) {
      int i = threadIdx.x + t * 256;
      v[t] = (i >= d) ? s[i - d] : 0;
    }
    __syncthreads();
    #pragma unroll
    for (int t = 0; t < 4; ++t) {
      int i = threadIdx.x + t * 256;
      s[i] += v[t];
    }
    __syncthreads();
  }
  #pragma unroll
  for (int t = 0; t < 4; ++t) {
    int i = threadIdx.x + t * 256;
    int idx = base + i;
    if (idx < N) incl[idx] = s[i];
  }
  if (threadIdx.x == 0) bsums[blockIdx.x] = s[1023];
}

// single block: exclusive scan of block sums (nb <= 1024)
__global__ __launch_bounds__(256) void k_scanB(const int* __restrict__ bsums,
                                               int* __restrict__ boff, int nb) {
  __shared__ int s[1024];
  #pragma unroll
  for (int t = 0; t < 4; ++t) {
    int i = threadIdx.x + t * 256;
    s[i] = (i < nb) ? bsums[i] : 0;
  }
  __syncthreads();
  for (int d = 1; d < 1024; d <<= 1) {
    int v[4];
    #pragma unroll
    for (int t = 0; t < 4; ++t) {
      int i = threadIdx.x + t * 256;
      v[t] = (i >= d) ? s[i - d] : 0;
    }
    __syncthreads();
    #pragma unroll
    for (int t = 0; t < 4; ++t) {
      int i = threadIdx.x + t * 256;
      s[i] += v[t];
    }
    __syncthreads();
  }
  #pragma unroll
  for (int t = 0; t < 4; ++t) {
    int i = threadIdx.x + t * 256;
    if (i < nb) boff[i] = (i == 0) ? 0 : s[i - 1];
  }
}

// finalize: exclusive rowptr, cursor copy, dinv. incl may alias rowptr.
__global__ void k_scanC(const int* __restrict__ cnt, const int* __restrict__ incl,
                        const int* __restrict__ boff, int* __restrict__ rowptr,
                        int* __restrict__ cursor, float* __restrict__ dinv, int N, int E) {
  int i = blockIdx.x * blockDim.x + threadIdx.x;
  if (i < N) {
    int ex = incl[i] - cnt[i] + boff[i >> 10];
    rowptr[i] = ex;
    cursor[i] = ex;
    dinv[i] = rsqrtf((float)(cnt[i] + 1));  // +1 self loop, always > 0
    if (i == 0) rowptr[N] = E;
  }
}

__global__ void k_scatter(const int* __restrict__ row, const int* __restrict__ col,
                          int* __restrict__ cursor, int* __restrict__ csr, int E) {
  int e = blockIdx.x * blockDim.x + threadIdx.x;
  if (e < E) {
    int c = col[e];
    int p = atomicAdd(&cursor[c], 1);
    csr[p] = row[e];
  }
}

// ---------------- gating: one wave per node, float4 loads, LDS histogram ----------------
__global__ __launch_bounds__(256) void k_gate(const float* __restrict__ x,
                                              const float* __restrict__ wg,
                                              int* __restrict__ eidx,
                                              int* __restrict__ meta, int N) {
  __shared__ int lhist[4];
  int tid = threadIdx.x;
  if (tid < 4) lhist[tid] = 0;
  __syncthreads();
  int wid = blockIdx.x * 4 + (tid >> 6);
  int lane = tid & 63;
  if (wid < N) {
    const float* xr = x + (size_t)wid * 512;
    float l0 = 0.f, l1 = 0.f, l2 = 0.f, l3 = 0.f;
    #pragma unroll
    for (int h = 0; h < 2; ++h) {
      int k0 = h * 256 + 4 * lane;
      float4 xv = *(const float4*)(xr + k0);
      float4 w0 = *(const float4*)(wg + 4 * (k0 + 0));
      float4 w1 = *(const float4*)(wg + 4 * (k0 + 1));
      float4 w2 = *(const float4*)(wg + 4 * (k0 + 2));
      float4 w3 = *(const float4*)(wg + 4 * (k0 + 3));
      l0 += xv.x * w0.x + xv.y * w1.x + xv.z * w2.x + xv.w * w3.x;
      l1 += xv.x * w0.y + xv.y * w1.y + xv.z * w2.y + xv.w * w3.y;
      l2 += xv.x * w0.z + xv.y * w1.z + xv.z * w2.z + xv.w * w3.z;
      l3 += xv.x * w0.w + xv.y * w1.w + xv.z * w2.w + xv.w * w3.w;
    }
    l0 = wave_reduce_sum(l0);
    l1 = wave_reduce_sum(l1);
    l2 = wave_reduce_sum(l2);
    l3 = wave_reduce_sum(l3);
    if (lane == 0) {
      int a = 0; float best = l0;
      if (l1 > best) { best = l1; a = 1; }
      if (l2 > best) { best = l2; a = 2; }
      if (l3 > best) { best = l3; a = 3; }
      eidx[wid] = a;
      atomicAdd(&lhist[a], 1);  // LDS atomic, 4 per block
    }
  }
  __syncthreads();
  if (tid < 4 && lhist[tid] > 0) atomicAdd(&meta[tid], lhist[tid]);  // 4 global atomics/block
}

// meta layout: [0..3] hist, [4..8] eoff, [9..13] toff, [14..17] ecur
__global__ void k_offs(int* meta) {
  if (threadIdx.x == 0 && blockIdx.x == 0) {
    int* hist = meta;
    int* eoff = meta + 4;
    int* toff = meta + 9;
    int* ecur = meta + 14;
    int s = 0, t = 0;
    eoff[0] = 0; toff[0] = 0;
    for (int e = 0; e < 4; ++e) {
      s += hist[e];
      eoff[e + 1] = s;
      t += (hist[e] + 63) / 64;
      toff[e + 1] = t;
      ecur[e] = eoff[e];
    }
  }
}

// bin nodes by expert: per-block LDS ranks + 4 global atomics per block
__global__ __launch_bounds__(256) void k_binscatter(const int* __restrict__ eidx,
                                                    int* __restrict__ meta,
                                                    int* __restrict__ perm, int N) {
  __shared__ int lhist[4];
  __shared__ int lbase[4];
  int tid = threadIdx.x;
  if (tid < 4) lhist[tid] = 0;
  __syncthreads();
  int n = blockIdx.x * 256 + tid;
  int e = 0, lrank = 0;
  bool valid = (n < N);
  if (valid) {
    e = eidx[n];
    lrank = atomicAdd(&lhist[e], 1);  // LDS atomic
  }
  __syncthreads();
  if (tid < 4) {
    int c = lhist[tid];
    lbase[tid] = (c > 0) ? atomicAdd(&meta[14 + tid], c) : 0;
  }
  __syncthreads();
  if (valid) perm[lbase[e] + lrank] = n;
}

// ---------------- expert GEMM: gathered rows, tiled 64x64x16 fp32 ----------------
__global__ __launch_bounds__(256) void k_gemm1(const float* __restrict__ x,
                                               const float* __restrict__ ew,
                                               const float* __restrict__ eb,
                                               const int* __restrict__ perm,
                                               const int* __restrict__ meta,
                                               float* __restrict__ h1, int N) {
  __shared__ float As[16][68];
  __shared__ float Bs[16][68];
  const int* eoff = meta + 4;
  const int* toff = meta + 9;
  int v = blockIdx.x;
  if (v >= toff[4]) return;
  int e = 0;
  while (v >= toff[e + 1]) ++e;
  int lt = v - toff[e];
  int m0 = eoff[e] + lt * 64;
  int mEnd = eoff[e + 1];
  int n0 = blockIdx.y * 64;
  int tid = threadIdx.x;

  int a_m = tid >> 2;           // 0..63
  int a_k = (tid & 3) * 4;      // 0,4,8,12
  int gm = m0 + a_m;
  int grow = (gm < mEnd) ? perm[gm] : -1;
  const float* arow = (grow >= 0) ? (x + (size_t)grow * 512) : x;

  int b_k = tid >> 4;           // 0..15
  int b_n = (tid & 15) * 4;     // 0..60
  const float* wbase = ew + (size_t)e * 512 * 256 + (size_t)n0 + b_n;

  int tm = (tid >> 4) * 4;
  int tn = (tid & 15) * 4;
  float acc[4][4] = {};

  for (int k0 = 0; k0 < 512; k0 += 16) {
    float4 av = make_float4(0.f, 0.f, 0.f, 0.f);
    if (grow >= 0) av = *(const float4*)(arow + k0 + a_k);
    As[a_k + 0][a_m] = av.x;
    As[a_k + 1][a_m] = av.y;
    As[a_k + 2][a_m] = av.z;
    As[a_k + 3][a_m] = av.w;
    float4 bv = *(const float4*)(wbase + (size_t)(k0 + b_k) * 256);
    *(float4*)&Bs[b_k][b_n] = bv;
    __syncthreads();
    #pragma unroll
    for (int k = 0; k < 16; ++k) {
      float4 a = *(float4*)&As[k][tm];
      float4 b = *(float4*)&Bs[k][tn];
      acc[0][0] += a.x * b.x; acc[0][1] += a.x * b.y; acc[0][2] += a.x * b.z; acc[0][3] += a.x * b.w;
      acc[1][0] += a.y * b.x; acc[1][1] += a.y * b.y; acc[1][2] += a.y * b.z; acc[1][3] += a.y * b.w;
      acc[2][0] += a.z * b.x; acc[2][1] += a.z * b.y; acc[2][2] += a.z * b.z; acc[2][3] += a.z * b.w;
      acc[3][0] += a.w * b.x; acc[3][1] += a.w * b.y; acc[3][2] += a.w * b.z; acc[3][3] += a.w * b.w;
    }
    __syncthreads();
  }

  #pragma unroll
  for (int i = 0; i < 4; ++i) {
    int m = m0 + tm + i;
    if (m < mEnd) {
      int g = perm[m];
      float4 bb = *(const float4*)(eb + (size_t)e * 256 + n0 + tn);
      float4 o = make_float4(acc[i][0] + bb.x, acc[i][1] + bb.y,
                             acc[i][2] + bb.z, acc[i][3] + bb.w);
      *(float4*)(h1 + (size_t)g * 256 + n0 + tn) = o;
    }
  }
}

// ---------------- propagate 1 (256 features): wave per destination ----------------
__global__ __launch_bounds__(256) void k_prop1(const float* __restrict__ h1,
                                               const int* __restrict__ rowptr,
                                               const int* __restrict__ csr,
                                               const float* __restrict__ dinv,
                                               const float* __restrict__ bias1,
                                               float* __restrict__ hrelu, int N) {
  int c = blockIdx.x * 4 + (threadIdx.x >> 6);
  int lane = threadIdx.x & 63;
  if (c >= N) return;
  float dc = dinv[c];
  const float4* hr = (const float4*)h1;
  float4 acc = hr[(size_t)c * 64 + lane];
  float sl = dc * dc;
  acc.x *= sl; acc.y *= sl; acc.z *= sl; acc.w *= sl;
  int jb = rowptr[c], je = rowptr[c + 1];
  for (int j = jb; j < je; ++j) {
    int r = csr[j];
    float s = dinv[r] * dc;
    float4 hv = hr[(size_t)r * 64 + lane];
    acc.x += hv.x * s; acc.y += hv.y * s; acc.z += hv.z * s; acc.w += hv.w * s;
  }
  float4 b = ((const float4*)bias1)[lane];
  acc.x = fmaxf(acc.x + b.x, 0.f);
  acc.y = fmaxf(acc.y + b.y, 0.f);
  acc.z = fmaxf(acc.z + b.z, 0.f);
  acc.w = fmaxf(acc.w + b.w, 0.f);
  ((float4*)hrelu)[(size_t)c * 64 + lane] = acc;
}

// ---------------- GEMM2: [N,256] x [256,64], tiled 64x64x16 fp32 ----------------
__global__ __launch_bounds__(256) void k_gemm2(const float* __restrict__ A,
                                               const float* __restrict__ B,
                                               float* __restrict__ C, int N) {
  __shared__ float As[16][68];
  __shared__ float Bs[16][68];
  int m0 = blockIdx.x * 64;
  int tid = threadIdx.x;
  int a_m = tid >> 2, a_k = (tid & 3) * 4;
  int b_k = tid >> 4, b_n = (tid & 15) * 4;
  int tm = (tid >> 4) * 4, tn = (tid & 15) * 4;
  int gm = m0 + a_m;
  const float* arow = A + (size_t)gm * 256;
  float acc[4][4] = {};

  for (int k0 = 0; k0 < 256; k0 += 16) {
    float4 av = make_float4(0.f, 0.f, 0.f, 0.f);
    if (gm < N) av = *(const float4*)(arow + k0 + a_k);
    As[a_k + 0][a_m] = av.x;
    As[a_k + 1][a_m] = av.y;
    As[a_k + 2][a_m] = av.z;
    As[a_k + 3][a_m] = av.w;
    float4 bv = *(const float4*)(B + (size_t)(k0 + b_k) * 64 + b_n);
    *(float4*)&Bs[b_k][b_n] = bv;
    __syncthreads();
    #pragma unroll
    for (int k = 0; k < 16; ++k) {
      float4 a = *(float4*)&As[k][tm];
      float4 b = *(float4*)&Bs[k][tn];
      acc[0][0] += a.x * b.x; acc[0][1] += a.x * b.y; acc[0][2] += a.x * b.z; acc[0][3] += a.x * b.w;
      acc[1][0] += a.y * b.x; acc[1][1] += a.y * b.y; acc[1][2] += a.y * b.z; acc[1][3] += a.y * b.w;
      acc[2][0] += a.z * b.x; acc[2][1] += a.z * b.y; acc[2][2] += a.z * b.z; acc[2][3] += a.z * b.w;
      acc[3][0] += a.w * b.x; acc[3][1] += a.w * b.y; acc[3][2] += a.w * b.z; acc[3][3] += a.w * b.w;
    }
    __syncthreads();
  }

  #pragma unroll
  for (int i = 0; i < 4; ++i) {
    int m = m0 + tm + i;
    if (m < N) {
      float4 o = make_float4(acc[i][0], acc[i][1], acc[i][2], acc[i][3]);
      *(float4*)(C + (size_t)m * 64 + tn) = o;
    }
  }
}

// ---------------- propagate 2 (64 features) + bias2 + log_softmax ----------------
__global__ __launch_bounds__(256) void k_prop2(const float* __restrict__ h3,
                                               const int* __restrict__ rowptr,
                                               const int* __restrict__ csr,
                                               const float* __restrict__ dinv,
                                               const float* __restrict__ bias2,
                                               float* __restrict__ out, int N) {
  int c = blockIdx.x * 4 + (threadIdx.x >> 6);
  int f = threadIdx.x & 63;
  if (c >= N) return;
  float dc = dinv[c];
  float acc = h3[(size_t)c * 64 + f] * dc * dc;
  int jb = rowptr[c], je = rowptr[c + 1];
  for (int j = jb; j < je; ++j) {
    int r = csr[j];
    acc += h3[(size_t)r * 64 + f] * (dinv[r] * dc);
  }
  acc += bias2[f];
  float m = wave_reduce_max(acc);
  float ex = expf(acc - m);
  float s = wave_reduce_sum(ex);
  out[(size_t)c * 64 + f] = acc - m - logf(s);
}

// ---------------- launch ----------------
extern "C" void kernel_launch(void* const* d_in, const int* in_sizes, int n_in,
                              void* d_out, int out_size, void* d_ws, size_t ws_size,
                              hipStream_t stream) {
  const float* x  = (const float*)d_in[0];
  const int*   ei = (const int*)d_in[1];
  const float* wg = (const float*)d_in[2];
  const float* ew = (const float*)d_in[3];
  const float* eb = (const float*)d_in[4];
  const float* b1 = (const float*)d_in[5];
  const float* w2 = (const float*)d_in[6];
  const float* b2 = (const float*)d_in[7];
  float* out = (float*)d_out;

  int N = in_sizes[0] / 512;
  int E = in_sizes[1] / 2;
  const int* row = ei;
  const int* col = ei + E;

  char* p = (char*)d_ws;
  auto alloc = [&](size_t bytes) -> void* {
    void* r = (void*)p;
    p += (bytes + 255) & ~(size_t)255;
    return r;
  };
  int*   cnt    = (int*)alloc((size_t)N * 4);
  int*   rowptr = (int*)alloc((size_t)(N + 1) * 4);
  int*   cursor = (int*)alloc((size_t)N * 4);
  int*   bsums  = (int*)alloc(1024 * 4);
  int*   boff   = (int*)alloc(1024 * 4);
  float* dinv   = (float*)alloc((size_t)N * 4);
  int*   eidx   = (int*)alloc((size_t)N * 4);
  int*   meta   = (int*)alloc(32 * 4);
  int*   perm   = (int*)alloc((size_t)N * 4);
  int*   csr    = (int*)alloc((size_t)E * 4);
  float* h1     = (float*)alloc((size_t)N * 256 * 4);
  float* hrelu  = (float*)alloc((size_t)N * 256 * 4);
  float* h3     = (float*)alloc((size_t)N * 64 * 4);

  int nb = (N + 1023) / 1024;

  k_init<<<(N + 255) / 256, 256, 0, stream>>>(cnt, meta, N);
  k_count<<<(E + 255) / 256, 256, 0, stream>>>(col, cnt, E);
  k_scanA<<<nb, 256, 0, stream>>>(cnt, rowptr, bsums, N);
  k_scanB<<<1, 256, 0, stream>>>(bsums, boff, nb);
  k_scanC<<<(N + 255) / 256, 256, 0, stream>>>(cnt, rowptr, boff, rowptr, cursor, dinv, N, E);
  k_scatter<<<(E + 255) / 256, 256, 0, stream>>>(row, col, cursor, csr, E);
  k_gate<<<(N + 3) / 4, 256, 0, stream>>>(x, wg, eidx, meta, N);
  k_offs<<<1, 64, 0, stream>>>(meta);
  k_binscatter<<<(N + 255) / 256, 256, 0, stream>>>(eidx, meta, perm, N);
  dim3 g1((N + 63) / 64 + 4, 4);
  k_gemm1<<<g1, 256, 0, stream>>>(x, ew, eb, perm, meta, h1, N);
  k_prop1<<<(N + 3) / 4, 256, 0, stream>>>(h1, rowptr, csr, dinv, b1, hrelu, N);
  k_gemm2<<<(N + 63) / 64, 256, 0, stream>>>(hrelu, w2, h3, N);
  k_prop2<<<(N + 3) / 4, 256, 0, stream>>>(h3, rowptr, csr, dinv, b2, out, N);
}

// Round 3
// 762.137 us; speedup vs baseline: 3.0909x; 1.4294x over previous
//
#include <hip/hip_runtime.h>
#include <math.h>

typedef __bf16 bf16x8 __attribute__((ext_vector_type(8)));
typedef float f32x16 __attribute__((ext_vector_type(16)));

// ---------------- helpers ----------------
__device__ __forceinline__ float wave_reduce_sum(float v) {
  #pragma unroll
  for (int off = 32; off > 0; off >>= 1) v += __shfl_xor(v, off, 64);
  return v;
}
__device__ __forceinline__ float wave_reduce_max(float v) {
  #pragma unroll
  for (int off = 32; off > 0; off >>= 1) v = fmaxf(v, __shfl_xor(v, off, 64));
  return v;
}
__device__ __forceinline__ unsigned short f2bf(float f) {
  union { float f; unsigned int u; } v; v.f = f;
  unsigned int r = (v.u + 0x7FFFu + ((v.u >> 16) & 1u)) >> 16;
  return (unsigned short)r;
}

// ---------------- setup kernels ----------------
__global__ void k_init(int* cnt, int* meta, int N) {
  int i = blockIdx.x * blockDim.x + threadIdx.x;
  if (i < N) cnt[i] = 0;
  if (i < 32) meta[i] = 0;
}

__global__ void k_count(const int* __restrict__ col, int* __restrict__ cnt, int E) {
  int e = blockIdx.x * blockDim.x + threadIdx.x;
  if (e < E) atomicAdd(&cnt[col[e]], 1);
}

__global__ __launch_bounds__(256) void k_scanA(const int* __restrict__ cnt,
                                               int* __restrict__ incl,
                                               int* __restrict__ bsums, int N) {
  __shared__ int s[1024];
  int base = blockIdx.x * 1024;
  #pragma unroll
  for (int t = 0; t < 4; ++t) {
    int i = threadIdx.x + t * 256;
    int idx = base + i;
    s[i] = (idx < N) ? cnt[idx] : 0;
  }
  __syncthreads();
  for (int d = 1; d < 1024; d <<= 1) {
    int v[4];
    #pragma unroll
    for (int t = 0; t < 4; ++t) {
      int i = threadIdx.x + t * 256;
      v[t] = (i >= d) ? s[i - d] : 0;
    }
    __syncthreads();
    #pragma unroll
    for (int t = 0; t < 4; ++t) {
      int i = threadIdx.x + t * 256;
      s[i] += v[t];
    }
    __syncthreads();
  }
  #pragma unroll
  for (int t = 0; t < 4; ++t) {
    int i = threadIdx.x + t * 256;
    int idx = base + i;
    if (idx < N) incl[idx] = s[i];
  }
  if (threadIdx.x == 0) bsums[blockIdx.x] = s[1023];
}

__global__ __launch_bounds__(256) void k_scanB(const int* __restrict__ bsums,
                                               int* __restrict__ boff, int nb) {
  __shared__ int s[1024];
  #pragma unroll
  for (int t = 0; t < 4; ++t) {
    int i = threadIdx.x + t * 256;
    s[i] = (i < nb) ? bsums[i] : 0;
  }
  __syncthreads();
  for (int d = 1; d < 1024; d <<= 1) {
    int v[4];
    #pragma unroll
    for (int t = 0; t < 4; ++t) {
      int i = threadIdx.x + t * 256;
      v[t] = (i >= d) ? s[i - d] : 0;
    }
    __syncthreads();
    #pragma unroll
    for (int t = 0; t < 4; ++t) {
      int i = threadIdx.x + t * 256;
      s[i] += v[t];
    }
    __syncthreads();
  }
  #pragma unroll
  for (int t = 0; t < 4; ++t) {
    int i = threadIdx.x + t * 256;
    if (i < nb) boff[i] = (i == 0) ? 0 : s[i - 1];
  }
}

__global__ void k_scanC(const int* __restrict__ cnt, const int* __restrict__ incl,
                        const int* __restrict__ boff, int* __restrict__ rowptr,
                        int* __restrict__ cursor, float* __restrict__ dinv, int N, int E) {
  int i = blockIdx.x * blockDim.x + threadIdx.x;
  if (i < N) {
    int ex = incl[i] - cnt[i] + boff[i >> 10];
    rowptr[i] = ex;
    cursor[i] = ex;
    dinv[i] = rsqrtf((float)(cnt[i] + 1));
    if (i == 0) rowptr[N] = E;
  }
}

__global__ void k_scatter(const int* __restrict__ row, const int* __restrict__ col,
                          int* __restrict__ cursor, int* __restrict__ csr, int E) {
  int e = blockIdx.x * blockDim.x + threadIdx.x;
  if (e < E) {
    int c = col[e];
    int p = atomicAdd(&cursor[c], 1);
    csr[p] = row[e];
  }
}

// ---------------- gating + fused fp32->bf16 conversion of x ----------------
__global__ __launch_bounds__(256) void k_gate(const float* __restrict__ x,
                                              const float* __restrict__ wg,
                                              int* __restrict__ eidx,
                                              int* __restrict__ meta,
                                              unsigned short* __restrict__ xb, int N) {
  __shared__ int lhist[4];
  int tid = threadIdx.x;
  if (tid < 4) lhist[tid] = 0;
  __syncthreads();
  int wid = blockIdx.x * 4 + (tid >> 6);
  int lane = tid & 63;
  if (wid < N) {
    const float* xr = x + (size_t)wid * 512;
    unsigned short* xbr = xb + (size_t)wid * 512;
    float l0 = 0.f, l1 = 0.f, l2 = 0.f, l3 = 0.f;
    #pragma unroll
    for (int h = 0; h < 2; ++h) {
      int k0 = h * 256 + 4 * lane;
      float4 xv = *(const float4*)(xr + k0);
      ushort4 ov;
      ov.x = f2bf(xv.x); ov.y = f2bf(xv.y); ov.z = f2bf(xv.z); ov.w = f2bf(xv.w);
      *(ushort4*)(xbr + k0) = ov;
      float4 w0 = *(const float4*)(wg + 4 * (k0 + 0));
      float4 w1 = *(const float4*)(wg + 4 * (k0 + 1));
      float4 w2 = *(const float4*)(wg + 4 * (k0 + 2));
      float4 w3 = *(const float4*)(wg + 4 * (k0 + 3));
      l0 += xv.x * w0.x + xv.y * w1.x + xv.z * w2.x + xv.w * w3.x;
      l1 += xv.x * w0.y + xv.y * w1.y + xv.z * w2.y + xv.w * w3.y;
      l2 += xv.x * w0.z + xv.y * w1.z + xv.z * w2.z + xv.w * w3.z;
      l3 += xv.x * w0.w + xv.y * w1.w + xv.z * w2.w + xv.w * w3.w;
    }
    l0 = wave_reduce_sum(l0);
    l1 = wave_reduce_sum(l1);
    l2 = wave_reduce_sum(l2);
    l3 = wave_reduce_sum(l3);
    if (lane == 0) {
      int a = 0; float best = l0;
      if (l1 > best) { best = l1; a = 1; }
      if (l2 > best) { best = l2; a = 2; }
      if (l3 > best) { best = l3; a = 3; }
      eidx[wid] = a;
      atomicAdd(&lhist[a], 1);
    }
  }
  __syncthreads();
  if (tid < 4 && lhist[tid] > 0) atomicAdd(&meta[tid], lhist[tid]);
}

// meta layout: [0..3] hist, [4..8] eoff, [9..13] toff, [14..17] ecur
// M-tile = 128 rows now.
__global__ void k_offs(int* meta) {
  if (threadIdx.x == 0 && blockIdx.x == 0) {
    int* hist = meta;
    int* eoff = meta + 4;
    int* toff = meta + 9;
    int* ecur = meta + 14;
    int s = 0, t = 0;
    eoff[0] = 0; toff[0] = 0;
    for (int e = 0; e < 4; ++e) {
      s += hist[e];
      eoff[e + 1] = s;
      t += (hist[e] + 127) / 128;
      toff[e + 1] = t;
      ecur[e] = eoff[e];
    }
  }
}

__global__ __launch_bounds__(256) void k_binscatter(const int* __restrict__ eidx,
                                                    int* __restrict__ meta,
                                                    int* __restrict__ perm, int N) {
  __shared__ int lhist[4];
  __shared__ int lbase[4];
  int tid = threadIdx.x;
  if (tid < 4) lhist[tid] = 0;
  __syncthreads();
  int n = blockIdx.x * 256 + tid;
  int e = 0, lrank = 0;
  bool valid = (n < N);
  if (valid) {
    e = eidx[n];
    lrank = atomicAdd(&lhist[e], 1);
  }
  __syncthreads();
  if (tid < 4) {
    int c = lhist[tid];
    lbase[tid] = (c > 0) ? atomicAdd(&meta[14 + tid], c) : 0;
  }
  __syncthreads();
  if (valid) perm[lbase[e] + lrank] = n;
}

// ---------------- pack expert weights: ewb[e][k/8][n][k%8] bf16 ----------------
__global__ __launch_bounds__(256) void k_pack(const float* __restrict__ ew,
                                              unsigned short* __restrict__ ewb) {
  int b = blockIdx.x;          // e*64 + kc
  int n = threadIdx.x;         // 0..255
  int e = b >> 6, kc = b & 63;
  const float* src = ew + ((size_t)e * 512 + (size_t)kc * 8) * 256 + n;
  unsigned short tmp[8];
  #pragma unroll
  for (int ke = 0; ke < 8; ++ke) tmp[ke] = f2bf(src[(size_t)ke * 256]);
  *(uint4*)(ewb + ((size_t)b * 256 + n) * 8) = *(const uint4*)tmp;
}

// ---------------- expert GEMM: bf16 MFMA 32x32x16, block tile 128x256 ----------------
__global__ __launch_bounds__(512, 2) void k_gemm1(const unsigned short* __restrict__ xb,
                                                  const unsigned short* __restrict__ ewb,
                                                  const float* __restrict__ eb,
                                                  const int* __restrict__ perm,
                                                  const int* __restrict__ meta,
                                                  float* __restrict__ h1) {
  __shared__ __align__(16) unsigned short A_lds[8192];    // [kcl 0..7][i 0..127][ke 0..7]
  __shared__ __align__(16) unsigned short B_lds[16384];   // [kcl 0..7][n 0..255][ke 0..7]
  __shared__ int sperm[128];
  const int* eoff = meta + 4;
  const int* toff = meta + 9;
  int v = blockIdx.x;
  if (v >= toff[4]) return;
  int e = 0;
  while (v >= toff[e + 1]) ++e;
  int m0 = eoff[e] + (v - toff[e]) * 128;
  int mEnd = eoff[e + 1];
  int tid = threadIdx.x;

  if (tid < 128) {
    int m = m0 + tid;
    sperm[tid] = perm[(m < mEnd) ? m : (mEnd - 1)];
  }
  __syncthreads();

  int wave = tid >> 6, lane = tid & 63;
  int wr = wave >> 2, wc = wave & 3;
  int hi = lane >> 5, lo = lane & 31;

  f32x16 acc[2][2];
  #pragma unroll
  for (int mi = 0; mi < 2; ++mi)
    #pragma unroll
    for (int ni = 0; ni < 2; ++ni)
      #pragma unroll
      for (int r = 0; r < 16; ++r) acc[mi][ni][r] = 0.f;

  const unsigned short* arow = xb + (size_t)sperm[tid & 127] * 512;
  int kclA = tid >> 7;  // 0..3 (t=0); +4 for t=1
  const uint4* ebase = (const uint4*)(ewb + (size_t)e * 64 * 2048);

  for (int k0 = 0; k0 < 512; k0 += 64) {
    // issue global loads (prev compute still in flight on other waves)
    uint4 a0 = *(const uint4*)(arow + k0 + kclA * 8);
    uint4 a1 = *(const uint4*)(arow + k0 + (kclA + 4) * 8);
    const uint4* bsrc = ebase + (size_t)(k0 >> 3) * 256;
    uint4 b0 = bsrc[tid];
    uint4 b1 = bsrc[512 + tid];
    uint4 b2 = bsrc[1024 + tid];
    uint4 b3 = bsrc[1536 + tid];
    __syncthreads();  // all waves done computing previous chunk
    *(uint4*)&A_lds[((size_t)kclA * 128 + (tid & 127)) * 8] = a0;
    *(uint4*)&A_lds[((size_t)(kclA + 4) * 128 + (tid & 127)) * 8] = a1;
    *(uint4*)&B_lds[((size_t)0 * 512 + tid) * 8] = b0;
    *(uint4*)&B_lds[((size_t)1 * 512 + tid) * 8] = b1;
    *(uint4*)&B_lds[((size_t)2 * 512 + tid) * 8] = b2;
    *(uint4*)&B_lds[((size_t)3 * 512 + tid) * 8] = b3;
    __syncthreads();
    #pragma unroll
    for (int s = 0; s < 4; ++s) {
      int kcl = s * 2 + hi;
      bf16x8 a0f = *(const bf16x8*)&A_lds[((size_t)kcl * 128 + wr * 64 + lo) * 8];
      bf16x8 a1f = *(const bf16x8*)&A_lds[((size_t)kcl * 128 + wr * 64 + 32 + lo) * 8];
      bf16x8 b0f = *(const bf16x8*)&B_lds[((size_t)kcl * 256 + wc * 64 + lo) * 8];
      bf16x8 b1f = *(const bf16x8*)&B_lds[((size_t)kcl * 256 + wc * 64 + 32 + lo) * 8];
      acc[0][0] = __builtin_amdgcn_mfma_f32_32x32x16_bf16(a0f, b0f, acc[0][0], 0, 0, 0);
      acc[0][1] = __builtin_amdgcn_mfma_f32_32x32x16_bf16(a0f, b1f, acc[0][1], 0, 0, 0);
      acc[1][0] = __builtin_amdgcn_mfma_f32_32x32x16_bf16(a1f, b0f, acc[1][0], 0, 0, 0);
      acc[1][1] = __builtin_amdgcn_mfma_f32_32x32x16_bf16(a1f, b1f, acc[1][1], 0, 0, 0);
    }
  }

  // epilogue: bias + scatter rows. C/D: col=lane&31, row=(reg&3)+8*(reg>>2)+4*(lane>>5)
  #pragma unroll
  for (int ni = 0; ni < 2; ++ni) {
    int col = wc * 64 + ni * 32 + lo;
    float bias = eb[e * 256 + col];
    #pragma unroll
    for (int mi = 0; mi < 2; ++mi) {
      #pragma unroll
      for (int q = 0; q < 4; ++q) {
        #pragma unroll
        for (int j = 0; j < 4; ++j) {
          int r = j + 8 * q + 4 * hi;
          int lrow = wr * 64 + mi * 32 + r;
          if (m0 + lrow < mEnd) {
            h1[(size_t)sperm[lrow] * 256 + col] = acc[mi][ni][q * 4 + j] + bias;
          }
        }
      }
    }
  }
}

// ---------------- propagate 1 (256 features): wave per destination ----------------
__global__ __launch_bounds__(256) void k_prop1(const float* __restrict__ h1,
                                               const int* __restrict__ rowptr,
                                               const int* __restrict__ csr,
                                               const float* __restrict__ dinv,
                                               const float* __restrict__ bias1,
                                               float* __restrict__ hrelu, int N) {
  int c = blockIdx.x * 4 + (threadIdx.x >> 6);
  int lane = threadIdx.x & 63;
  if (c >= N) return;
  float dc = dinv[c];
  const float4* hr = (const float4*)h1;
  float4 acc = hr[(size_t)c * 64 + lane];
  float sl = dc * dc;
  acc.x *= sl; acc.y *= sl; acc.z *= sl; acc.w *= sl;
  int jb = rowptr[c], je = rowptr[c + 1];
  for (int j = jb; j < je; ++j) {
    int r = csr[j];
    float s = dinv[r] * dc;
    float4 hv = hr[(size_t)r * 64 + lane];
    acc.x += hv.x * s; acc.y += hv.y * s; acc.z += hv.z * s; acc.w += hv.w * s;
  }
  float4 b = ((const float4*)bias1)[lane];
  acc.x = fmaxf(acc.x + b.x, 0.f);
  acc.y = fmaxf(acc.y + b.y, 0.f);
  acc.z = fmaxf(acc.z + b.z, 0.f);
  acc.w = fmaxf(acc.w + b.w, 0.f);
  ((float4*)hrelu)[(size_t)c * 64 + lane] = acc;
}

// ---------------- GEMM2: [N,256] x [256,64], tiled 64x64x16 fp32 ----------------
__global__ __launch_bounds__(256) void k_gemm2(const float* __restrict__ A,
                                               const float* __restrict__ B,
                                               float* __restrict__ C, int N) {
  __shared__ float As[16][68];
  __shared__ float Bs[16][68];
  int m0 = blockIdx.x * 64;
  int tid = threadIdx.x;
  int a_m = tid >> 2, a_k = (tid & 3) * 4;
  int b_k = tid >> 4, b_n = (tid & 15) * 4;
  int tm = (tid >> 4) * 4, tn = (tid & 15) * 4;
  int gm = m0 + a_m;
  const float* arow = A + (size_t)gm * 256;
  float acc[4][4] = {};

  for (int k0 = 0; k0 < 256; k0 += 16) {
    float4 av = make_float4(0.f, 0.f, 0.f, 0.f);
    if (gm < N) av = *(const float4*)(arow + k0 + a_k);
    As[a_k + 0][a_m] = av.x;
    As[a_k + 1][a_m] = av.y;
    As[a_k + 2][a_m] = av.z;
    As[a_k + 3][a_m] = av.w;
    float4 bv = *(const float4*)(B + (size_t)(k0 + b_k) * 64 + b_n);
    *(float4*)&Bs[b_k][b_n] = bv;
    __syncthreads();
    #pragma unroll
    for (int k = 0; k < 16; ++k) {
      float4 a = *(float4*)&As[k][tm];
      float4 b = *(float4*)&Bs[k][tn];
      acc[0][0] += a.x * b.x; acc[0][1] += a.x * b.y; acc[0][2] += a.x * b.z; acc[0][3] += a.x * b.w;
      acc[1][0] += a.y * b.x; acc[1][1] += a.y * b.y; acc[1][2] += a.y * b.z; acc[1][3] += a.y * b.w;
      acc[2][0] += a.z * b.x; acc[2][1] += a.z * b.y; acc[2][2] += a.z * b.z; acc[2][3] += a.z * b.w;
      acc[3][0] += a.w * b.x; acc[3][1] += a.w * b.y; acc[3][2] += a.w * b.z; acc[3][3] += a.w * b.w;
    }
    __syncthreads();
  }

  #pragma unroll
  for (int i = 0; i < 4; ++i) {
    int m = m0 + tm + i;
    if (m < N) {
      float4 o = make_float4(acc[i][0], acc[i][1], acc[i][2], acc[i][3]);
      *(float4*)(C + (size_t)m * 64 + tn) = o;
    }
  }
}

// ---------------- propagate 2 (64 features) + bias2 + log_softmax ----------------
__global__ __launch_bounds__(256) void k_prop2(const float* __restrict__ h3,
                                               const int* __restrict__ rowptr,
                                               const int* __restrict__ csr,
                                               const float* __restrict__ dinv,
                                               const float* __restrict__ bias2,
                                               float* __restrict__ out, int N) {
  int c = blockIdx.x * 4 + (threadIdx.x >> 6);
  int f = threadIdx.x & 63;
  if (c >= N) return;
  float dc = dinv[c];
  float acc = h3[(size_t)c * 64 + f] * dc * dc;
  int jb = rowptr[c], je = rowptr[c + 1];
  for (int j = jb; j < je; ++j) {
    int r = csr[j];
    acc += h3[(size_t)r * 64 + f] * (dinv[r] * dc);
  }
  acc += bias2[f];
  float m = wave_reduce_max(acc);
  float ex = expf(acc - m);
  float s = wave_reduce_sum(ex);
  out[(size_t)c * 64 + f] = acc - m - logf(s);
}

// ---------------- launch ----------------
extern "C" void kernel_launch(void* const* d_in, const int* in_sizes, int n_in,
                              void* d_out, int out_size, void* d_ws, size_t ws_size,
                              hipStream_t stream) {
  const float* x  = (const float*)d_in[0];
  const int*   ei = (const int*)d_in[1];
  const float* wg = (const float*)d_in[2];
  const float* ew = (const float*)d_in[3];
  const float* eb = (const float*)d_in[4];
  const float* b1 = (const float*)d_in[5];
  const float* w2 = (const float*)d_in[6];
  const float* b2 = (const float*)d_in[7];
  float* out = (float*)d_out;

  int N = in_sizes[0] / 512;
  int E = in_sizes[1] / 2;
  const int* row = ei;
  const int* col = ei + E;

  char* p = (char*)d_ws;
  auto alloc = [&](size_t bytes) -> void* {
    void* r = (void*)p;
    p += (bytes + 255) & ~(size_t)255;
    return r;
  };
  int*   cnt    = (int*)alloc((size_t)N * 4);
  int*   rowptr = (int*)alloc((size_t)(N + 1) * 4);
  int*   cursor = (int*)alloc((size_t)N * 4);
  int*   bsums  = (int*)alloc(1024 * 4);
  int*   boff   = (int*)alloc(1024 * 4);
  float* dinv   = (float*)alloc((size_t)N * 4);
  int*   eidx   = (int*)alloc((size_t)N * 4);
  int*   meta   = (int*)alloc(32 * 4);
  int*   perm   = (int*)alloc((size_t)N * 4);
  int*   csr    = (int*)alloc((size_t)E * 4);
  float* h1     = (float*)alloc((size_t)N * 256 * 4);
  float* hrelu  = (float*)alloc((size_t)N * 256 * 4);
  float* h3     = (float*)alloc((size_t)N * 64 * 4);
  unsigned short* xb  = (unsigned short*)alloc((size_t)N * 512 * 2);
  unsigned short* ewb = (unsigned short*)alloc((size_t)4 * 512 * 256 * 2);

  int nb = (N + 1023) / 1024;

  k_init<<<(N + 255) / 256, 256, 0, stream>>>(cnt, meta, N);
  k_count<<<(E + 255) / 256, 256, 0, stream>>>(col, cnt, E);
  k_scanA<<<nb, 256, 0, stream>>>(cnt, rowptr, bsums, N);
  k_scanB<<<1, 256, 0, stream>>>(bsums, boff, nb);
  k_scanC<<<(N + 255) / 256, 256, 0, stream>>>(cnt, rowptr, boff, rowptr, cursor, dinv, N, E);
  k_scatter<<<(E + 255) / 256, 256, 0, stream>>>(row, col, cursor, csr, E);
  k_pack<<<256, 256, 0, stream>>>(ew, ewb);
  k_gate<<<(N + 3) / 4, 256, 0, stream>>>(x, wg, eidx, meta, xb, N);
  k_offs<<<1, 64, 0, stream>>>(meta);
  k_binscatter<<<(N + 255) / 256, 256, 0, stream>>>(eidx, meta, perm, N);
  int ntiles = (N + 127) / 128 + 4;
  k_gemm1<<<ntiles, 512, 0, stream>>>(xb, ewb, eb, perm, meta, h1);
  k_prop1<<<(N + 3) / 4, 256, 0, stream>>>(h1, rowptr, csr, dinv, b1, hrelu, N);
  k_gemm2<<<(N + 63) / 64, 256, 0, stream>>>(hrelu, w2, h3, N);
  k_prop2<<<(N + 3) / 4, 256, 0, stream>>>(h3, rowptr, csr, dinv, b2, out, N);
}

// Round 4
// 555.437 us; speedup vs baseline: 4.2411x; 1.3721x over previous
//
#include <hip/hip_runtime.h>
#include <math.h>

typedef __bf16 bf16x8 __attribute__((ext_vector_type(8)));
typedef float f32x16 __attribute__((ext_vector_type(16)));

// ---------------- helpers ----------------
__device__ __forceinline__ float wave_reduce_sum(float v) {
  #pragma unroll
  for (int off = 32; off > 0; off >>= 1) v += __shfl_xor(v, off, 64);
  return v;
}
__device__ __forceinline__ float wave_reduce_max(float v) {
  #pragma unroll
  for (int off = 32; off > 0; off >>= 1) v = fmaxf(v, __shfl_xor(v, off, 64));
  return v;
}
__device__ __forceinline__ unsigned short f2bf(float f) {
  union { float f; unsigned int u; } v; v.f = f;
  unsigned int r = (v.u + 0x7FFFu + ((v.u >> 16) & 1u)) >> 16;
  return (unsigned short)r;
}

// ---------------- setup kernels ----------------
__global__ void k_init(int* cnt, int* meta, int N) {
  int i = blockIdx.x * blockDim.x + threadIdx.x;
  if (i < N) cnt[i] = 0;
  if (i < 32) meta[i] = 0;
}

__global__ void k_count(const int* __restrict__ col, int* __restrict__ cnt, int E) {
  int e = blockIdx.x * blockDim.x + threadIdx.x;
  if (e < E) atomicAdd(&cnt[col[e]], 1);
}

__global__ __launch_bounds__(256) void k_scanA(const int* __restrict__ cnt,
                                               int* __restrict__ incl,
                                               int* __restrict__ bsums, int N) {
  __shared__ int s[1024];
  int base = blockIdx.x * 1024;
  #pragma unroll
  for (int t = 0; t < 4; ++t) {
    int i = threadIdx.x + t * 256;
    int idx = base + i;
    s[i] = (idx < N) ? cnt[idx] : 0;
  }
  __syncthreads();
  for (int d = 1; d < 1024; d <<= 1) {
    int v[4];
    #pragma unroll
    for (int t = 0; t < 4; ++t) {
      int i = threadIdx.x + t * 256;
      v[t] = (i >= d) ? s[i - d] : 0;
    }
    __syncthreads();
    #pragma unroll
    for (int t = 0; t < 4; ++t) {
      int i = threadIdx.x + t * 256;
      s[i] += v[t];
    }
    __syncthreads();
  }
  #pragma unroll
  for (int t = 0; t < 4; ++t) {
    int i = threadIdx.x + t * 256;
    int idx = base + i;
    if (idx < N) incl[idx] = s[i];
  }
  if (threadIdx.x == 0) bsums[blockIdx.x] = s[1023];
}

__global__ __launch_bounds__(256) void k_scanB(const int* __restrict__ bsums,
                                               int* __restrict__ boff, int nb) {
  __shared__ int s[1024];
  #pragma unroll
  for (int t = 0; t < 4; ++t) {
    int i = threadIdx.x + t * 256;
    s[i] = (i < nb) ? bsums[i] : 0;
  }
  __syncthreads();
  for (int d = 1; d < 1024; d <<= 1) {
    int v[4];
    #pragma unroll
    for (int t = 0; t < 4; ++t) {
      int i = threadIdx.x + t * 256;
      v[t] = (i >= d) ? s[i - d] : 0;
    }
    __syncthreads();
    #pragma unroll
    for (int t = 0; t < 4; ++t) {
      int i = threadIdx.x + t * 256;
      s[i] += v[t];
    }
    __syncthreads();
  }
  #pragma unroll
  for (int t = 0; t < 4; ++t) {
    int i = threadIdx.x + t * 256;
    if (i < nb) boff[i] = (i == 0) ? 0 : s[i - 1];
  }
}

__global__ void k_scanC(const int* __restrict__ cnt, const int* __restrict__ incl,
                        const int* __restrict__ boff, int* __restrict__ rowptr,
                        int* __restrict__ cursor, float* __restrict__ dinv, int N, int E) {
  int i = blockIdx.x * blockDim.x + threadIdx.x;
  if (i < N) {
    int ex = incl[i] - cnt[i] + boff[i >> 10];
    rowptr[i] = ex;
    cursor[i] = ex;
    dinv[i] = rsqrtf((float)(cnt[i] + 1));
    if (i == 0) rowptr[N] = E;
  }
}

__global__ void k_scatter(const int* __restrict__ row, const int* __restrict__ col,
                          int* __restrict__ cursor, int* __restrict__ csr, int E) {
  int e = blockIdx.x * blockDim.x + threadIdx.x;
  if (e < E) {
    int c = col[e];
    int p = atomicAdd(&cursor[c], 1);
    csr[p] = row[e];
  }
}

// ---------------- gating + fused fp32->bf16 conversion of x ----------------
// 16 lanes per node, 16 nodes per 256-thread block.
__global__ __launch_bounds__(256) void k_gate(const float* __restrict__ x,
                                              const float* __restrict__ wg,
                                              int* __restrict__ eidx,
                                              int* __restrict__ meta,
                                              unsigned short* __restrict__ xb, int N) {
  __shared__ int lhist[4];
  int tid = threadIdx.x;
  if (tid < 4) lhist[tid] = 0;
  __syncthreads();
  int node = blockIdx.x * 16 + (tid >> 4);
  int sl = tid & 15;
  if (node < N) {
    const float* xr = x + (size_t)node * 512;
    unsigned short* xbr = xb + (size_t)node * 512;
    float l0 = 0.f, l1 = 0.f, l2 = 0.f, l3 = 0.f;
    #pragma unroll
    for (int j = 0; j < 8; ++j) {
      int q = sl + 16 * j;             // float4 index within row, 0..127
      float4 xv = *(const float4*)(xr + 4 * q);
      ushort4 ov;
      ov.x = f2bf(xv.x); ov.y = f2bf(xv.y); ov.z = f2bf(xv.z); ov.w = f2bf(xv.w);
      *(ushort4*)(xbr + 4 * q) = ov;
      float4 w0 = *(const float4*)(wg + 4 * (4 * q + 0));
      float4 w1 = *(const float4*)(wg + 4 * (4 * q + 1));
      float4 w2 = *(const float4*)(wg + 4 * (4 * q + 2));
      float4 w3 = *(const float4*)(wg + 4 * (4 * q + 3));
      l0 += xv.x * w0.x + xv.y * w1.x + xv.z * w2.x + xv.w * w3.x;
      l1 += xv.x * w0.y + xv.y * w1.y + xv.z * w2.y + xv.w * w3.y;
      l2 += xv.x * w0.z + xv.y * w1.z + xv.z * w2.z + xv.w * w3.z;
      l3 += xv.x * w0.w + xv.y * w1.w + xv.z * w2.w + xv.w * w3.w;
    }
    #pragma unroll
    for (int off = 8; off > 0; off >>= 1) {
      l0 += __shfl_xor(l0, off, 64);
      l1 += __shfl_xor(l1, off, 64);
      l2 += __shfl_xor(l2, off, 64);
      l3 += __shfl_xor(l3, off, 64);
    }
    if (sl == 0) {
      int a = 0; float best = l0;
      if (l1 > best) { best = l1; a = 1; }
      if (l2 > best) { best = l2; a = 2; }
      if (l3 > best) { best = l3; a = 3; }
      eidx[node] = a;
      atomicAdd(&lhist[a], 1);
    }
  }
  __syncthreads();
  if (tid < 4 && lhist[tid] > 0) atomicAdd(&meta[tid], lhist[tid]);
}

// meta layout: [0..3] hist, [4..8] eoff, [9..13] toff, [14..17] ecur
// M-tile = 128 rows.
__global__ void k_offs(int* meta) {
  if (threadIdx.x == 0 && blockIdx.x == 0) {
    int* hist = meta;
    int* eoff = meta + 4;
    int* toff = meta + 9;
    int* ecur = meta + 14;
    int s = 0, t = 0;
    eoff[0] = 0; toff[0] = 0;
    for (int e = 0; e < 4; ++e) {
      s += hist[e];
      eoff[e + 1] = s;
      t += (hist[e] + 127) / 128;
      toff[e + 1] = t;
      ecur[e] = eoff[e];
    }
  }
}

__global__ __launch_bounds__(256) void k_binscatter(const int* __restrict__ eidx,
                                                    int* __restrict__ meta,
                                                    int* __restrict__ perm, int N) {
  __shared__ int lhist[4];
  __shared__ int lbase[4];
  int tid = threadIdx.x;
  if (tid < 4) lhist[tid] = 0;
  __syncthreads();
  int n = blockIdx.x * 256 + tid;
  int e = 0, lrank = 0;
  bool valid = (n < N);
  if (valid) {
    e = eidx[n];
    lrank = atomicAdd(&lhist[e], 1);
  }
  __syncthreads();
  if (tid < 4) {
    int c = lhist[tid];
    lbase[tid] = (c > 0) ? atomicAdd(&meta[14 + tid], c) : 0;
  }
  __syncthreads();
  if (valid) perm[lbase[e] + lrank] = n;
}

// ---------------- pack expert weights: ewb[e][k/8][n][k%8] bf16 ----------------
__global__ __launch_bounds__(256) void k_pack(const float* __restrict__ ew,
                                              unsigned short* __restrict__ ewb) {
  int b = blockIdx.x;          // e*64 + kc
  int n = threadIdx.x;         // 0..255
  int e = b >> 6, kc = b & 63;
  const float* src = ew + ((size_t)e * 512 + (size_t)kc * 8) * 256 + n;
  unsigned short tmp[8];
  #pragma unroll
  for (int ke = 0; ke < 8; ++ke) tmp[ke] = f2bf(src[(size_t)ke * 256]);
  *(uint4*)(ewb + ((size_t)b * 256 + n) * 8) = *(const uint4*)tmp;
}

// ---------------- expert GEMM: bf16 MFMA 32x32x16, block tile 128x256 ----------------
__global__ __launch_bounds__(512, 2) void k_gemm1(const unsigned short* __restrict__ xb,
                                                  const unsigned short* __restrict__ ewb,
                                                  const float* __restrict__ eb,
                                                  const int* __restrict__ perm,
                                                  const int* __restrict__ meta,
                                                  float* __restrict__ h1) {
  __shared__ __align__(16) unsigned short A_lds[8192];    // [kcl 0..7][i 0..127][ke 0..7]
  __shared__ __align__(16) unsigned short B_lds[16384];   // [kcl 0..7][n 0..255][ke 0..7]
  __shared__ int sperm[128];
  const int* eoff = meta + 4;
  const int* toff = meta + 9;
  int v = blockIdx.x;
  if (v >= toff[4]) return;
  int e = 0;
  while (v >= toff[e + 1]) ++e;
  int m0 = eoff[e] + (v - toff[e]) * 128;
  int mEnd = eoff[e + 1];
  int tid = threadIdx.x;

  if (tid < 128) {
    int m = m0 + tid;
    sperm[tid] = perm[(m < mEnd) ? m : (mEnd - 1)];
  }
  __syncthreads();

  int wave = tid >> 6, lane = tid & 63;
  int wr = wave >> 2, wc = wave & 3;
  int hi = lane >> 5, lo = lane & 31;

  f32x16 acc[2][2];
  #pragma unroll
  for (int mi = 0; mi < 2; ++mi)
    #pragma unroll
    for (int ni = 0; ni < 2; ++ni)
      #pragma unroll
      for (int r = 0; r < 16; ++r) acc[mi][ni][r] = 0.f;

  const unsigned short* arow = xb + (size_t)sperm[tid & 127] * 512;
  int kclA = tid >> 7;  // 0..3 (t=0); +4 for t=1
  const uint4* ebase = (const uint4*)(ewb + (size_t)e * 64 * 2048);

  for (int k0 = 0; k0 < 512; k0 += 64) {
    uint4 a0 = *(const uint4*)(arow + k0 + kclA * 8);
    uint4 a1 = *(const uint4*)(arow + k0 + (kclA + 4) * 8);
    const uint4* bsrc = ebase + (size_t)(k0 >> 3) * 256;
    uint4 b0 = bsrc[tid];
    uint4 b1 = bsrc[512 + tid];
    uint4 b2 = bsrc[1024 + tid];
    uint4 b3 = bsrc[1536 + tid];
    __syncthreads();
    *(uint4*)&A_lds[((size_t)kclA * 128 + (tid & 127)) * 8] = a0;
    *(uint4*)&A_lds[((size_t)(kclA + 4) * 128 + (tid & 127)) * 8] = a1;
    *(uint4*)&B_lds[((size_t)0 * 512 + tid) * 8] = b0;
    *(uint4*)&B_lds[((size_t)1 * 512 + tid) * 8] = b1;
    *(uint4*)&B_lds[((size_t)2 * 512 + tid) * 8] = b2;
    *(uint4*)&B_lds[((size_t)3 * 512 + tid) * 8] = b3;
    __syncthreads();
    #pragma unroll
    for (int s = 0; s < 4; ++s) {
      int kcl = s * 2 + hi;
      bf16x8 a0f = *(const bf16x8*)&A_lds[((size_t)kcl * 128 + wr * 64 + lo) * 8];
      bf16x8 a1f = *(const bf16x8*)&A_lds[((size_t)kcl * 128 + wr * 64 + 32 + lo) * 8];
      bf16x8 b0f = *(const bf16x8*)&B_lds[((size_t)kcl * 256 + wc * 64 + lo) * 8];
      bf16x8 b1f = *(const bf16x8*)&B_lds[((size_t)kcl * 256 + wc * 64 + 32 + lo) * 8];
      acc[0][0] = __builtin_amdgcn_mfma_f32_32x32x16_bf16(a0f, b0f, acc[0][0], 0, 0, 0);
      acc[0][1] = __builtin_amdgcn_mfma_f32_32x32x16_bf16(a0f, b1f, acc[0][1], 0, 0, 0);
      acc[1][0] = __builtin_amdgcn_mfma_f32_32x32x16_bf16(a1f, b0f, acc[1][0], 0, 0, 0);
      acc[1][1] = __builtin_amdgcn_mfma_f32_32x32x16_bf16(a1f, b1f, acc[1][1], 0, 0, 0);
    }
  }

  // epilogue: bias + scatter rows. C/D: col=lane&31, row=(reg&3)+8*(reg>>2)+4*(lane>>5)
  #pragma unroll
  for (int ni = 0; ni < 2; ++ni) {
    int col = wc * 64 + ni * 32 + lo;
    float bias = eb[e * 256 + col];
    #pragma unroll
    for (int mi = 0; mi < 2; ++mi) {
      #pragma unroll
      for (int q = 0; q < 4; ++q) {
        #pragma unroll
        for (int j = 0; j < 4; ++j) {
          int r = j + 8 * q + 4 * hi;
          int lrow = wr * 64 + mi * 32 + r;
          if (m0 + lrow < mEnd) {
            h1[(size_t)sperm[lrow] * 256 + col] = acc[mi][ni][q * 4 + j] + bias;
          }
        }
      }
    }
  }
}

// ---------------- propagate 1 (256 features): wave per destination ----------------
__global__ __launch_bounds__(256) void k_prop1(const float* __restrict__ h1,
                                               const int* __restrict__ rowptr,
                                               const int* __restrict__ csr,
                                               const float* __restrict__ dinv,
                                               const float* __restrict__ bias1,
                                               float* __restrict__ hrelu, int N) {
  int c = blockIdx.x * 4 + (threadIdx.x >> 6);
  int lane = threadIdx.x & 63;
  if (c >= N) return;
  float dc = dinv[c];
  const float4* hr = (const float4*)h1;
  float4 acc = hr[(size_t)c * 64 + lane];
  float sl = dc * dc;
  acc.x *= sl; acc.y *= sl; acc.z *= sl; acc.w *= sl;
  int jb = rowptr[c], je = rowptr[c + 1];
  for (int j = jb; j < je; ++j) {
    int r = csr[j];
    float s = dinv[r] * dc;
    float4 hv = hr[(size_t)r * 64 + lane];
    acc.x += hv.x * s; acc.y += hv.y * s; acc.z += hv.z * s; acc.w += hv.w * s;
  }
  float4 b = ((const float4*)bias1)[lane];
  acc.x = fmaxf(acc.x + b.x, 0.f);
  acc.y = fmaxf(acc.y + b.y, 0.f);
  acc.z = fmaxf(acc.z + b.z, 0.f);
  acc.w = fmaxf(acc.w + b.w, 0.f);
  ((float4*)hrelu)[(size_t)c * 64 + lane] = acc;
}

// ---------------- GEMM2: [N,256] x [256,64], tiled 64x64x16 fp32 ----------------
__global__ __launch_bounds__(256) void k_gemm2(const float* __restrict__ A,
                                               const float* __restrict__ B,
                                               float* __restrict__ C, int N) {
  __shared__ float As[16][68];
  __shared__ float Bs[16][68];
  int m0 = blockIdx.x * 64;
  int tid = threadIdx.x;
  int a_m = tid >> 2, a_k = (tid & 3) * 4;
  int b_k = tid >> 4, b_n = (tid & 15) * 4;
  int tm = (tid >> 4) * 4, tn = (tid & 15) * 4;
  int gm = m0 + a_m;
  const float* arow = A + (size_t)gm * 256;
  float acc[4][4] = {};

  for (int k0 = 0; k0 < 256; k0 += 16) {
    float4 av = make_float4(0.f, 0.f, 0.f, 0.f);
    if (gm < N) av = *(const float4*)(arow + k0 + a_k);
    As[a_k + 0][a_m] = av.x;
    As[a_k + 1][a_m] = av.y;
    As[a_k + 2][a_m] = av.z;
    As[a_k + 3][a_m] = av.w;
    float4 bv = *(const float4*)(B + (size_t)(k0 + b_k) * 64 + b_n);
    *(float4*)&Bs[b_k][b_n] = bv;
    __syncthreads();
    #pragma unroll
    for (int k = 0; k < 16; ++k) {
      float4 a = *(float4*)&As[k][tm];
      float4 b = *(float4*)&Bs[k][tn];
      acc[0][0] += a.x * b.x; acc[0][1] += a.x * b.y; acc[0][2] += a.x * b.z; acc[0][3] += a.x * b.w;
      acc[1][0] += a.y * b.x; acc[1][1] += a.y * b.y; acc[1][2] += a.y * b.z; acc[1][3] += a.y * b.w;
      acc[2][0] += a.z * b.x; acc[2][1] += a.z * b.y; acc[2][2] += a.z * b.z; acc[2][3] += a.z * b.w;
      acc[3][0] += a.w * b.x; acc[3][1] += a.w * b.y; acc[3][2] += a.w * b.z; acc[3][3] += a.w * b.w;
    }
    __syncthreads();
  }

  #pragma unroll
  for (int i = 0; i < 4; ++i) {
    int m = m0 + tm + i;
    if (m < N) {
      float4 o = make_float4(acc[i][0], acc[i][1], acc[i][2], acc[i][3]);
      *(float4*)(C + (size_t)m * 64 + tn) = o;
    }
  }
}

// ---------------- propagate 2 (64 features) + bias2 + log_softmax ----------------
__global__ __launch_bounds__(256) void k_prop2(const float* __restrict__ h3,
                                               const int* __restrict__ rowptr,
                                               const int* __restrict__ csr,
                                               const float* __restrict__ dinv,
                                               const float* __restrict__ bias2,
                                               float* __restrict__ out, int N) {
  int c = blockIdx.x * 4 + (threadIdx.x >> 6);
  int f = threadIdx.x & 63;
  if (c >= N) return;
  float dc = dinv[c];
  float acc = h3[(size_t)c * 64 + f] * dc * dc;
  int jb = rowptr[c], je = rowptr[c + 1];
  for (int j = jb; j < je; ++j) {
    int r = csr[j];
    acc += h3[(size_t)r * 64 + f] * (dinv[r] * dc);
  }
  acc += bias2[f];
  float m = wave_reduce_max(acc);
  float ex = expf(acc - m);
  float s = wave_reduce_sum(ex);
  out[(size_t)c * 64 + f] = acc - m - logf(s);
}

// ---------------- launch ----------------
extern "C" void kernel_launch(void* const* d_in, const int* in_sizes, int n_in,
                              void* d_out, int out_size, void* d_ws, size_t ws_size,
                              hipStream_t stream) {
  const float* x  = (const float*)d_in[0];
  const int*   ei = (const int*)d_in[1];
  const float* wg = (const float*)d_in[2];
  const float* ew = (const float*)d_in[3];
  const float* eb = (const float*)d_in[4];
  const float* b1 = (const float*)d_in[5];
  const float* w2 = (const float*)d_in[6];
  const float* b2 = (const float*)d_in[7];
  float* out = (float*)d_out;

  int N = in_sizes[0] / 512;
  int E = in_sizes[1] / 2;
  const int* row = ei;
  const int* col = ei + E;

  char* p = (char*)d_ws;
  auto alloc = [&](size_t bytes) -> void* {
    void* r = (void*)p;
    p += (bytes + 255) & ~(size_t)255;
    return r;
  };
  int*   cnt    = (int*)alloc((size_t)N * 4);
  int*   rowptr = (int*)alloc((size_t)(N + 1) * 4);
  int*   cursor = (int*)alloc((size_t)N * 4);
  int*   bsums  = (int*)alloc(1024 * 4);
  int*   boff   = (int*)alloc(1024 * 4);
  float* dinv   = (float*)alloc((size_t)N * 4);
  int*   eidx   = (int*)alloc((size_t)N * 4);
  int*   meta   = (int*)alloc(32 * 4);
  int*   perm   = (int*)alloc((size_t)N * 4);
  int*   csr    = (int*)alloc((size_t)E * 4);
  float* h1     = (float*)alloc((size_t)N * 256 * 4);
  float* hrelu  = (float*)alloc((size_t)N * 256 * 4);
  float* h3     = (float*)alloc((size_t)N * 64 * 4);
  unsigned short* xb  = (unsigned short*)alloc((size_t)N * 512 * 2);
  unsigned short* ewb = (unsigned short*)alloc((size_t)4 * 512 * 256 * 2);

  int nb = (N + 1023) / 1024;

  k_init<<<(N + 255) / 256, 256, 0, stream>>>(cnt, meta, N);
  k_count<<<(E + 255) / 256, 256, 0, stream>>>(col, cnt, E);
  k_scanA<<<nb, 256, 0, stream>>>(cnt, rowptr, bsums, N);
  k_scanB<<<1, 256, 0, stream>>>(bsums, boff, nb);
  k_scanC<<<(N + 255) / 256, 256, 0, stream>>>(cnt, rowptr, boff, rowptr, cursor, dinv, N, E);
  k_scatter<<<(E + 255) / 256, 256, 0, stream>>>(row, col, cursor, csr, E);
  k_pack<<<256, 256, 0, stream>>>(ew, ewb);
  k_gate<<<(N + 15) / 16, 256, 0, stream>>>(x, wg, eidx, meta, xb, N);
  k_offs<<<1, 64, 0, stream>>>(meta);
  k_binscatter<<<(N + 255) / 256, 256, 0, stream>>>(eidx, meta, perm, N);
  int ntiles = (N + 127) / 128 + 4;
  k_gemm1<<<ntiles, 512, 0, stream>>>(xb, ewb, eb, perm, meta, h1);
  k_prop1<<<(N + 3) / 4, 256, 0, stream>>>(h1, rowptr, csr, dinv, b1, hrelu, N);
  k_gemm2<<<(N + 63) / 64, 256, 0, stream>>>(hrelu, w2, h3, N);
  k_prop2<<<(N + 3) / 4, 256, 0, stream>>>(h3, rowptr, csr, dinv, b2, out, N);
}

// Round 5
// 516.419 us; speedup vs baseline: 4.5616x; 1.0756x over previous
//
#include <hip/hip_runtime.h>
#include <math.h>

typedef __bf16 bf16x8 __attribute__((ext_vector_type(8)));
typedef float f32x16 __attribute__((ext_vector_type(16)));

// ---------------- helpers ----------------
__device__ __forceinline__ float wave_reduce_sum(float v) {
  #pragma unroll
  for (int off = 32; off > 0; off >>= 1) v += __shfl_xor(v, off, 64);
  return v;
}
__device__ __forceinline__ float wave_reduce_max(float v) {
  #pragma unroll
  for (int off = 32; off > 0; off >>= 1) v = fmaxf(v, __shfl_xor(v, off, 64));
  return v;
}
__device__ __forceinline__ unsigned short f2bf(float f) {
  union { float f; unsigned int u; } v; v.f = f;
  unsigned int r = (v.u + 0x7FFFu + ((v.u >> 16) & 1u)) >> 16;
  return (unsigned short)r;
}
__device__ __forceinline__ float bf2f(unsigned short u) {
  union { unsigned int u; float f; } v; v.u = ((unsigned int)u) << 16;
  return v.f;
}

// ---------------- setup kernels ----------------
__global__ void k_init(int* cnt, int* meta, int N) {
  int i = blockIdx.x * blockDim.x + threadIdx.x;
  if (i < N) cnt[i] = 0;
  if (i < 32) meta[i] = 0;
}

__global__ void k_count(const int* __restrict__ col, int* __restrict__ cnt, int E) {
  int e = blockIdx.x * blockDim.x + threadIdx.x;
  if (e < E) atomicAdd(&cnt[col[e]], 1);
}

__global__ __launch_bounds__(256) void k_scanA(const int* __restrict__ cnt,
                                               int* __restrict__ incl,
                                               int* __restrict__ bsums, int N) {
  __shared__ int s[1024];
  int base = blockIdx.x * 1024;
  #pragma unroll
  for (int t = 0; t < 4; ++t) {
    int i = threadIdx.x + t * 256;
    int idx = base + i;
    s[i] = (idx < N) ? cnt[idx] : 0;
  }
  __syncthreads();
  for (int d = 1; d < 1024; d <<= 1) {
    int v[4];
    #pragma unroll
    for (int t = 0; t < 4; ++t) {
      int i = threadIdx.x + t * 256;
      v[t] = (i >= d) ? s[i - d] : 0;
    }
    __syncthreads();
    #pragma unroll
    for (int t = 0; t < 4; ++t) {
      int i = threadIdx.x + t * 256;
      s[i] += v[t];
    }
    __syncthreads();
  }
  #pragma unroll
  for (int t = 0; t < 4; ++t) {
    int i = threadIdx.x + t * 256;
    int idx = base + i;
    if (idx < N) incl[idx] = s[i];
  }
  if (threadIdx.x == 0) bsums[blockIdx.x] = s[1023];
}

__global__ __launch_bounds__(256) void k_scanB(const int* __restrict__ bsums,
                                               int* __restrict__ boff, int nb) {
  __shared__ int s[1024];
  #pragma unroll
  for (int t = 0; t < 4; ++t) {
    int i = threadIdx.x + t * 256;
    s[i] = (i < nb) ? bsums[i] : 0;
  }
  __syncthreads();
  for (int d = 1; d < 1024; d <<= 1) {
    int v[4];
    #pragma unroll
    for (int t = 0; t < 4; ++t) {
      int i = threadIdx.x + t * 256;
      v[t] = (i >= d) ? s[i - d] : 0;
    }
    __syncthreads();
    #pragma unroll
    for (int t = 0; t < 4; ++t) {
      int i = threadIdx.x + t * 256;
      s[i] += v[t];
    }
    __syncthreads();
  }
  #pragma unroll
  for (int t = 0; t < 4; ++t) {
    int i = threadIdx.x + t * 256;
    if (i < nb) boff[i] = (i == 0) ? 0 : s[i - 1];
  }
}

__global__ void k_scanC(const int* __restrict__ cnt, const int* __restrict__ incl,
                        const int* __restrict__ boff, int* __restrict__ rowptr,
                        int* __restrict__ cursor, float* __restrict__ dinv, int N, int E) {
  int i = blockIdx.x * blockDim.x + threadIdx.x;
  if (i < N) {
    int ex = incl[i] - cnt[i] + boff[i >> 10];
    rowptr[i] = ex;
    cursor[i] = ex;
    dinv[i] = rsqrtf((float)(cnt[i] + 1));
    if (i == 0) rowptr[N] = E;
  }
}

__global__ void k_scatter(const int* __restrict__ row, const int* __restrict__ col,
                          int* __restrict__ cursor, int* __restrict__ csr, int E) {
  int e = blockIdx.x * blockDim.x + threadIdx.x;
  if (e < E) {
    int c = col[e];
    int p = atomicAdd(&cursor[c], 1);
    csr[p] = row[e];
  }
}

// ---------------- gating + fused fp32->bf16 conversion of x ----------------
// 16 lanes per node, 16 nodes per 256-thread block.
__global__ __launch_bounds__(256) void k_gate(const float* __restrict__ x,
                                              const float* __restrict__ wg,
                                              int* __restrict__ eidx,
                                              int* __restrict__ meta,
                                              unsigned short* __restrict__ xb, int N) {
  __shared__ int lhist[4];
  int tid = threadIdx.x;
  if (tid < 4) lhist[tid] = 0;
  __syncthreads();
  int node = blockIdx.x * 16 + (tid >> 4);
  int sl = tid & 15;
  if (node < N) {
    const float* xr = x + (size_t)node * 512;
    unsigned short* xbr = xb + (size_t)node * 512;
    float l0 = 0.f, l1 = 0.f, l2 = 0.f, l3 = 0.f;
    #pragma unroll
    for (int j = 0; j < 8; ++j) {
      int q = sl + 16 * j;             // float4 index within row, 0..127
      float4 xv = *(const float4*)(xr + 4 * q);
      ushort4 ov;
      ov.x = f2bf(xv.x); ov.y = f2bf(xv.y); ov.z = f2bf(xv.z); ov.w = f2bf(xv.w);
      *(ushort4*)(xbr + 4 * q) = ov;
      float4 w0 = *(const float4*)(wg + 4 * (4 * q + 0));
      float4 w1 = *(const float4*)(wg + 4 * (4 * q + 1));
      float4 w2 = *(const float4*)(wg + 4 * (4 * q + 2));
      float4 w3 = *(const float4*)(wg + 4 * (4 * q + 3));
      l0 += xv.x * w0.x + xv.y * w1.x + xv.z * w2.x + xv.w * w3.x;
      l1 += xv.x * w0.y + xv.y * w1.y + xv.z * w2.y + xv.w * w3.y;
      l2 += xv.x * w0.z + xv.y * w1.z + xv.z * w2.z + xv.w * w3.z;
      l3 += xv.x * w0.w + xv.y * w1.w + xv.z * w2.w + xv.w * w3.w;
    }
    #pragma unroll
    for (int off = 8; off > 0; off >>= 1) {
      l0 += __shfl_xor(l0, off, 64);
      l1 += __shfl_xor(l1, off, 64);
      l2 += __shfl_xor(l2, off, 64);
      l3 += __shfl_xor(l3, off, 64);
    }
    if (sl == 0) {
      int a = 0; float best = l0;
      if (l1 > best) { best = l1; a = 1; }
      if (l2 > best) { best = l2; a = 2; }
      if (l3 > best) { best = l3; a = 3; }
      eidx[node] = a;
      atomicAdd(&lhist[a], 1);
    }
  }
  __syncthreads();
  if (tid < 4 && lhist[tid] > 0) atomicAdd(&meta[tid], lhist[tid]);
}

// meta layout: [0..3] hist, [4..8] eoff, [9..13] toff, [14..17] ecur
// M-tile = 128 rows.
__global__ void k_offs(int* meta) {
  if (threadIdx.x == 0 && blockIdx.x == 0) {
    int* hist = meta;
    int* eoff = meta + 4;
    int* toff = meta + 9;
    int* ecur = meta + 14;
    int s = 0, t = 0;
    eoff[0] = 0; toff[0] = 0;
    for (int e = 0; e < 4; ++e) {
      s += hist[e];
      eoff[e + 1] = s;
      t += (hist[e] + 127) / 128;
      toff[e + 1] = t;
      ecur[e] = eoff[e];
    }
  }
}

__global__ __launch_bounds__(256) void k_binscatter(const int* __restrict__ eidx,
                                                    int* __restrict__ meta,
                                                    int* __restrict__ perm, int N) {
  __shared__ int lhist[4];
  __shared__ int lbase[4];
  int tid = threadIdx.x;
  if (tid < 4) lhist[tid] = 0;
  __syncthreads();
  int n = blockIdx.x * 256 + tid;
  int e = 0, lrank = 0;
  bool valid = (n < N);
  if (valid) {
    e = eidx[n];
    lrank = atomicAdd(&lhist[e], 1);
  }
  __syncthreads();
  if (tid < 4) {
    int c = lhist[tid];
    lbase[tid] = (c > 0) ? atomicAdd(&meta[14 + tid], c) : 0;
  }
  __syncthreads();
  if (valid) perm[lbase[e] + lrank] = n;
}

// ---------------- pack expert weights: ewb[e][k/8][n][k%8] bf16 ----------------
__global__ __launch_bounds__(256) void k_pack(const float* __restrict__ ew,
                                              unsigned short* __restrict__ ewb) {
  int b = blockIdx.x;          // e*64 + kc
  int n = threadIdx.x;         // 0..255
  int e = b >> 6, kc = b & 63;
  const float* src = ew + ((size_t)e * 512 + (size_t)kc * 8) * 256 + n;
  unsigned short tmp[8];
  #pragma unroll
  for (int ke = 0; ke < 8; ++ke) tmp[ke] = f2bf(src[(size_t)ke * 256]);
  *(uint4*)(ewb + ((size_t)b * 256 + n) * 8) = *(const uint4*)tmp;
}

// ---------------- pack w2: w2b[k/8][n][k%8] bf16 (K=256, n=64) ----------------
__global__ __launch_bounds__(64) void k_pack2(const float* __restrict__ w2,
                                              unsigned short* __restrict__ w2b) {
  int kc = blockIdx.x;         // 0..31
  int n = threadIdx.x;         // 0..63
  const float* src = w2 + (size_t)kc * 8 * 64 + n;
  unsigned short tmp[8];
  #pragma unroll
  for (int ke = 0; ke < 8; ++ke) tmp[ke] = f2bf(src[(size_t)ke * 64]);
  *(uint4*)(w2b + ((size_t)kc * 64 + n) * 8) = *(const uint4*)tmp;
}

// ---------------- expert GEMM: bf16 MFMA 32x32x16, block tile 128x256 ----------------
__global__ __launch_bounds__(512, 2) void k_gemm1(const unsigned short* __restrict__ xb,
                                                  const unsigned short* __restrict__ ewb,
                                                  const float* __restrict__ eb,
                                                  const int* __restrict__ perm,
                                                  const int* __restrict__ meta,
                                                  unsigned short* __restrict__ h1) {
  __shared__ __align__(16) unsigned short A_lds[8192];    // [kcl 0..7][i 0..127][ke 0..7]
  __shared__ __align__(16) unsigned short B_lds[16384];   // [kcl 0..7][n 0..255][ke 0..7]
  __shared__ int sperm[128];
  const int* eoff = meta + 4;
  const int* toff = meta + 9;
  int v = blockIdx.x;
  if (v >= toff[4]) return;
  int e = 0;
  while (v >= toff[e + 1]) ++e;
  int m0 = eoff[e] + (v - toff[e]) * 128;
  int mEnd = eoff[e + 1];
  int tid = threadIdx.x;

  if (tid < 128) {
    int m = m0 + tid;
    sperm[tid] = perm[(m < mEnd) ? m : (mEnd - 1)];
  }
  __syncthreads();

  int wave = tid >> 6, lane = tid & 63;
  int wr = wave >> 2, wc = wave & 3;
  int hi = lane >> 5, lo = lane & 31;

  f32x16 acc[2][2];
  #pragma unroll
  for (int mi = 0; mi < 2; ++mi)
    #pragma unroll
    for (int ni = 0; ni < 2; ++ni)
      #pragma unroll
      for (int r = 0; r < 16; ++r) acc[mi][ni][r] = 0.f;

  const unsigned short* arow = xb + (size_t)sperm[tid & 127] * 512;
  int kclA = tid >> 7;  // 0..3 (t=0); +4 for t=1
  const uint4* ebase = (const uint4*)(ewb + (size_t)e * 64 * 2048);

  for (int k0 = 0; k0 < 512; k0 += 64) {
    uint4 a0 = *(const uint4*)(arow + k0 + kclA * 8);
    uint4 a1 = *(const uint4*)(arow + k0 + (kclA + 4) * 8);
    const uint4* bsrc = ebase + (size_t)(k0 >> 3) * 256;
    uint4 b0 = bsrc[tid];
    uint4 b1 = bsrc[512 + tid];
    uint4 b2 = bsrc[1024 + tid];
    uint4 b3 = bsrc[1536 + tid];
    __syncthreads();
    *(uint4*)&A_lds[((size_t)kclA * 128 + (tid & 127)) * 8] = a0;
    *(uint4*)&A_lds[((size_t)(kclA + 4) * 128 + (tid & 127)) * 8] = a1;
    *(uint4*)&B_lds[((size_t)0 * 512 + tid) * 8] = b0;
    *(uint4*)&B_lds[((size_t)1 * 512 + tid) * 8] = b1;
    *(uint4*)&B_lds[((size_t)2 * 512 + tid) * 8] = b2;
    *(uint4*)&B_lds[((size_t)3 * 512 + tid) * 8] = b3;
    __syncthreads();
    #pragma unroll
    for (int s = 0; s < 4; ++s) {
      int kcl = s * 2 + hi;
      bf16x8 a0f = *(const bf16x8*)&A_lds[((size_t)kcl * 128 + wr * 64 + lo) * 8];
      bf16x8 a1f = *(const bf16x8*)&A_lds[((size_t)kcl * 128 + wr * 64 + 32 + lo) * 8];
      bf16x8 b0f = *(const bf16x8*)&B_lds[((size_t)kcl * 256 + wc * 64 + lo) * 8];
      bf16x8 b1f = *(const bf16x8*)&B_lds[((size_t)kcl * 256 + wc * 64 + 32 + lo) * 8];
      acc[0][0] = __builtin_amdgcn_mfma_f32_32x32x16_bf16(a0f, b0f, acc[0][0], 0, 0, 0);
      acc[0][1] = __builtin_amdgcn_mfma_f32_32x32x16_bf16(a0f, b1f, acc[0][1], 0, 0, 0);
      acc[1][0] = __builtin_amdgcn_mfma_f32_32x32x16_bf16(a1f, b0f, acc[1][0], 0, 0, 0);
      acc[1][1] = __builtin_amdgcn_mfma_f32_32x32x16_bf16(a1f, b1f, acc[1][1], 0, 0, 0);
    }
  }

  // epilogue: bias + scatter rows as bf16. C/D: col=lane&31, row=(reg&3)+8*(reg>>2)+4*(lane>>5)
  #pragma unroll
  for (int ni = 0; ni < 2; ++ni) {
    int col = wc * 64 + ni * 32 + lo;
    float bias = eb[e * 256 + col];
    #pragma unroll
    for (int mi = 0; mi < 2; ++mi) {
      #pragma unroll
      for (int q = 0; q < 4; ++q) {
        #pragma unroll
        for (int j = 0; j < 4; ++j) {
          int r = j + 8 * q + 4 * hi;
          int lrow = wr * 64 + mi * 32 + r;
          if (m0 + lrow < mEnd) {
            h1[(size_t)sperm[lrow] * 256 + col] = f2bf(acc[mi][ni][q * 4 + j] + bias);
          }
        }
      }
    }
  }
}

// ---------------- propagate 1 (256 feat, bf16 in/out): wave per destination ----------------
__global__ __launch_bounds__(256) void k_prop1(const unsigned short* __restrict__ h1,
                                               const int* __restrict__ rowptr,
                                               const int* __restrict__ csr,
                                               const float* __restrict__ dinv,
                                               const float* __restrict__ bias1,
                                               unsigned short* __restrict__ hrelu, int N) {
  int c = blockIdx.x * 4 + (threadIdx.x >> 6);
  int lane = threadIdx.x & 63;
  if (c >= N) return;
  float dc = dinv[c];
  const ushort4* hr = (const ushort4*)h1;  // row = 64 ushort4
  ushort4 sv = hr[(size_t)c * 64 + lane];
  float sl = dc * dc;
  float ax = bf2f(sv.x) * sl, ay = bf2f(sv.y) * sl, az = bf2f(sv.z) * sl, aw = bf2f(sv.w) * sl;
  int jb = rowptr[c], je = rowptr[c + 1];
  for (int j = jb; j < je; ++j) {
    int r = csr[j];
    float s = dinv[r] * dc;
    ushort4 hv = hr[(size_t)r * 64 + lane];
    ax += bf2f(hv.x) * s; ay += bf2f(hv.y) * s; az += bf2f(hv.z) * s; aw += bf2f(hv.w) * s;
  }
  float4 b = ((const float4*)bias1)[lane];
  ushort4 ov;
  ov.x = f2bf(fmaxf(ax + b.x, 0.f));
  ov.y = f2bf(fmaxf(ay + b.y, 0.f));
  ov.z = f2bf(fmaxf(az + b.z, 0.f));
  ov.w = f2bf(fmaxf(aw + b.w, 0.f));
  ((ushort4*)hrelu)[(size_t)c * 64 + lane] = ov;
}

// ---------------- GEMM2: bf16 MFMA, [N,256]x[256,64], block tile 128x64 ----------------
__global__ __launch_bounds__(256, 2) void k_gemm2(const unsigned short* __restrict__ A,
                                                  const unsigned short* __restrict__ w2b,
                                                  unsigned short* __restrict__ h3, int N) {
  __shared__ __align__(16) unsigned short B_lds[16384];  // [kc 0..31][n 0..63][ke 0..7]
  __shared__ __align__(16) unsigned short A_lds[8192];   // [kcl 0..7][i 0..127][ke 0..7]
  int tid = threadIdx.x;
  int m0 = blockIdx.x * 128;
  #pragma unroll
  for (int it = 0; it < 8; ++it)
    *(uint4*)&B_lds[((size_t)it * 256 + tid) * 8] = ((const uint4*)w2b)[it * 256 + tid];

  int wave = tid >> 6, lane = tid & 63;
  int wr = wave >> 1, wc = wave & 1;
  int hi = lane >> 5, lo = lane & 31;

  f32x16 acc[2];
  #pragma unroll
  for (int mi = 0; mi < 2; ++mi)
    #pragma unroll
    for (int r = 0; r < 16; ++r) acc[mi][r] = 0.f;

  int i = tid & 127;
  int row = m0 + i;
  if (row >= N) row = N - 1;
  const unsigned short* arow = A + (size_t)row * 256;
  int kcl0 = tid >> 7;  // 0..1

  for (int k0 = 0; k0 < 256; k0 += 64) {
    uint4 a[4];
    #pragma unroll
    for (int t = 0; t < 4; ++t)
      a[t] = *(const uint4*)(arow + k0 + (kcl0 + 2 * t) * 8);
    __syncthreads();
    #pragma unroll
    for (int t = 0; t < 4; ++t)
      *(uint4*)&A_lds[((size_t)(kcl0 + 2 * t) * 128 + i) * 8] = a[t];
    __syncthreads();
    #pragma unroll
    for (int s = 0; s < 4; ++s) {
      int kcl = s * 2 + hi;
      bf16x8 a0f = *(const bf16x8*)&A_lds[((size_t)kcl * 128 + wr * 64 + lo) * 8];
      bf16x8 a1f = *(const bf16x8*)&A_lds[((size_t)kcl * 128 + wr * 64 + 32 + lo) * 8];
      bf16x8 bf = *(const bf16x8*)&B_lds[(((size_t)(k0 >> 3) + kcl) * 64 + wc * 32 + lo) * 8];
      acc[0] = __builtin_amdgcn_mfma_f32_32x32x16_bf16(a0f, bf, acc[0], 0, 0, 0);
      acc[1] = __builtin_amdgcn_mfma_f32_32x32x16_bf16(a1f, bf, acc[1], 0, 0, 0);
    }
  }

  int n = wc * 32 + lo;
  #pragma unroll
  for (int mi = 0; mi < 2; ++mi) {
    #pragma unroll
    for (int q = 0; q < 4; ++q) {
      #pragma unroll
      for (int j = 0; j < 4; ++j) {
        int r = j + 8 * q + 4 * hi;
        int orow = m0 + wr * 64 + mi * 32 + r;
        if (orow < N) h3[(size_t)orow * 64 + n] = f2bf(acc[mi][q * 4 + j]);
      }
    }
  }
}

// ---------------- propagate 2 (64 feat, bf16 in) + bias2 + log_softmax ----------------
__global__ __launch_bounds__(256) void k_prop2(const unsigned short* __restrict__ h3,
                                               const int* __restrict__ rowptr,
                                               const int* __restrict__ csr,
                                               const float* __restrict__ dinv,
                                               const float* __restrict__ bias2,
                                               float* __restrict__ out, int N) {
  int c = blockIdx.x * 4 + (threadIdx.x >> 6);
  int f = threadIdx.x & 63;
  if (c >= N) return;
  float dc = dinv[c];
  float acc = bf2f(h3[(size_t)c * 64 + f]) * dc * dc;
  int jb = rowptr[c], je = rowptr[c + 1];
  for (int j = jb; j < je; ++j) {
    int r = csr[j];
    acc += bf2f(h3[(size_t)r * 64 + f]) * (dinv[r] * dc);
  }
  acc += bias2[f];
  float m = wave_reduce_max(acc);
  float ex = expf(acc - m);
  float s = wave_reduce_sum(ex);
  out[(size_t)c * 64 + f] = acc - m - logf(s);
}

// ---------------- launch ----------------
extern "C" void kernel_launch(void* const* d_in, const int* in_sizes, int n_in,
                              void* d_out, int out_size, void* d_ws, size_t ws_size,
                              hipStream_t stream) {
  const float* x  = (const float*)d_in[0];
  const int*   ei = (const int*)d_in[1];
  const float* wg = (const float*)d_in[2];
  const float* ew = (const float*)d_in[3];
  const float* eb = (const float*)d_in[4];
  const float* b1 = (const float*)d_in[5];
  const float* w2 = (const float*)d_in[6];
  const float* b2 = (const float*)d_in[7];
  float* out = (float*)d_out;

  int N = in_sizes[0] / 512;
  int E = in_sizes[1] / 2;
  const int* row = ei;
  const int* col = ei + E;

  char* p = (char*)d_ws;
  auto alloc = [&](size_t bytes) -> void* {
    void* r = (void*)p;
    p += (bytes + 255) & ~(size_t)255;
    return r;
  };
  int*   cnt    = (int*)alloc((size_t)N * 4);
  int*   rowptr = (int*)alloc((size_t)(N + 1) * 4);
  int*   cursor = (int*)alloc((size_t)N * 4);
  int*   bsums  = (int*)alloc(1024 * 4);
  int*   boff   = (int*)alloc(1024 * 4);
  float* dinv   = (float*)alloc((size_t)N * 4);
  int*   eidx   = (int*)alloc((size_t)N * 4);
  int*   meta   = (int*)alloc(32 * 4);
  int*   perm   = (int*)alloc((size_t)N * 4);
  int*   csr    = (int*)alloc((size_t)E * 4);
  unsigned short* h1    = (unsigned short*)alloc((size_t)N * 256 * 2);
  unsigned short* hrelu = (unsigned short*)alloc((size_t)N * 256 * 2);
  unsigned short* h3    = (unsigned short*)alloc((size_t)N * 64 * 2);
  unsigned short* xb  = (unsigned short*)alloc((size_t)N * 512 * 2);
  unsigned short* ewb = (unsigned short*)alloc((size_t)4 * 512 * 256 * 2);
  unsigned short* w2b = (unsigned short*)alloc((size_t)256 * 64 * 2);

  int nb = (N + 1023) / 1024;

  k_init<<<(N + 255) / 256, 256, 0, stream>>>(cnt, meta, N);
  k_count<<<(E + 255) / 256, 256, 0, stream>>>(col, cnt, E);
  k_scanA<<<nb, 256, 0, stream>>>(cnt, rowptr, bsums, N);
  k_scanB<<<1, 256, 0, stream>>>(bsums, boff, nb);
  k_scanC<<<(N + 255) / 256, 256, 0, stream>>>(cnt, rowptr, boff, rowptr, cursor, dinv, N, E);
  k_scatter<<<(E + 255) / 256, 256, 0, stream>>>(row, col, cursor, csr, E);
  k_pack<<<256, 256, 0, stream>>>(ew, ewb);
  k_pack2<<<32, 64, 0, stream>>>(w2, w2b);
  k_gate<<<(N + 15) / 16, 256, 0, stream>>>(x, wg, eidx, meta, xb, N);
  k_offs<<<1, 64, 0, stream>>>(meta);
  k_binscatter<<<(N + 255) / 256, 256, 0, stream>>>(eidx, meta, perm, N);
  int ntiles = (N + 127) / 128 + 4;
  k_gemm1<<<ntiles, 512, 0, stream>>>(xb, ewb, eb, perm, meta, h1);
  k_prop1<<<(N + 3) / 4, 256, 0, stream>>>(h1, rowptr, csr, dinv, b1, hrelu, N);
  k_gemm2<<<(N + 127) / 128, 256, 0, stream>>>(hrelu, w2b, h3, N);
  k_prop2<<<(N + 3) / 4, 256, 0, stream>>>(h3, rowptr, csr, dinv, b2, out, N);
}

// Round 6
// 425.504 us; speedup vs baseline: 5.5362x; 1.2137x over previous
//
#include <hip/hip_runtime.h>
#include <math.h>

typedef __bf16 bf16x8 __attribute__((ext_vector_type(8)));
typedef float f32x16 __attribute__((ext_vector_type(16)));

// ---------------- helpers ----------------
__device__ __forceinline__ float wave_reduce_sum(float v) {
  #pragma unroll
  for (int off = 32; off > 0; off >>= 1) v += __shfl_xor(v, off, 64);
  return v;
}
__device__ __forceinline__ float wave_reduce_max(float v) {
  #pragma unroll
  for (int off = 32; off > 0; off >>= 1) v = fmaxf(v, __shfl_xor(v, off, 64));
  return v;
}
__device__ __forceinline__ unsigned short f2bf(float f) {
  union { float f; unsigned int u; } v; v.f = f;
  unsigned int r = (v.u + 0x7FFFu + ((v.u >> 16) & 1u)) >> 16;
  return (unsigned short)r;
}
__device__ __forceinline__ float bf2f(unsigned short u) {
  union { unsigned int u; float f; } v; v.u = ((unsigned int)u) << 16;
  return v.f;
}

// ---------------- setup kernels ----------------
__global__ void k_init(int* cnt, int* meta, int N) {
  int i = blockIdx.x * blockDim.x + threadIdx.x;
  if (i < N) cnt[i] = 0;
  if (i < 32) meta[i] = 0;
}

__global__ void k_count(const int* __restrict__ col, int* __restrict__ cnt, int E) {
  int e = blockIdx.x * blockDim.x + threadIdx.x;
  if (e < E) atomicAdd(&cnt[col[e]], 1);
}

__global__ __launch_bounds__(256) void k_scanA(const int* __restrict__ cnt,
                                               int* __restrict__ incl,
                                               int* __restrict__ bsums, int N) {
  __shared__ int s[1024];
  int base = blockIdx.x * 1024;
  #pragma unroll
  for (int t = 0; t < 4; ++t) {
    int i = threadIdx.x + t * 256;
    int idx = base + i;
    s[i] = (idx < N) ? cnt[idx] : 0;
  }
  __syncthreads();
  for (int d = 1; d < 1024; d <<= 1) {
    int v[4];
    #pragma unroll
    for (int t = 0; t < 4; ++t) {
      int i = threadIdx.x + t * 256;
      v[t] = (i >= d) ? s[i - d] : 0;
    }
    __syncthreads();
    #pragma unroll
    for (int t = 0; t < 4; ++t) {
      int i = threadIdx.x + t * 256;
      s[i] += v[t];
    }
    __syncthreads();
  }
  #pragma unroll
  for (int t = 0; t < 4; ++t) {
    int i = threadIdx.x + t * 256;
    int idx = base + i;
    if (idx < N) incl[idx] = s[i];
  }
  if (threadIdx.x == 0) bsums[blockIdx.x] = s[1023];
}

__global__ __launch_bounds__(256) void k_scanB(const int* __restrict__ bsums,
                                               int* __restrict__ boff, int nb) {
  __shared__ int s[1024];
  #pragma unroll
  for (int t = 0; t < 4; ++t) {
    int i = threadIdx.x + t * 256;
    s[i] = (i < nb) ? bsums[i] : 0;
  }
  __syncthreads();
  for (int d = 1; d < 1024; d <<= 1) {
    int v[4];
    #pragma unroll
    for (int t = 0; t < 4; ++t) {
      int i = threadIdx.x + t * 256;
      v[t] = (i >= d) ? s[i - d] : 0;
    }
    __syncthreads();
    #pragma unroll
    for (int t = 0; t < 4; ++t) {
      int i = threadIdx.x + t * 256;
      s[i] += v[t];
    }
    __syncthreads();
  }
  #pragma unroll
  for (int t = 0; t < 4; ++t) {
    int i = threadIdx.x + t * 256;
    if (i < nb) boff[i] = (i == 0) ? 0 : s[i - 1];
  }
}

__global__ void k_scanC(const int* __restrict__ cnt, const int* __restrict__ incl,
                        const int* __restrict__ boff, int* __restrict__ rowptr,
                        int* __restrict__ cursor, float* __restrict__ dinv, int N, int E) {
  int i = blockIdx.x * blockDim.x + threadIdx.x;
  if (i < N) {
    int ex = incl[i] - cnt[i] + boff[i >> 10];
    rowptr[i] = ex;
    cursor[i] = ex;
    dinv[i] = rsqrtf((float)(cnt[i] + 1));
    if (i == 0) rowptr[N] = E;
  }
}

__global__ void k_scatter(const int* __restrict__ row, const int* __restrict__ col,
                          int* __restrict__ cursor, int* __restrict__ csr, int E) {
  int e = blockIdx.x * blockDim.x + threadIdx.x;
  if (e < E) {
    int c = col[e];
    int p = atomicAdd(&cursor[c], 1);
    csr[p] = row[e];
  }
}

// ---------------- gating + fused fp32->bf16 conversion of x ----------------
// 16 lanes per node, 16 nodes per 256-thread block.
__global__ __launch_bounds__(256) void k_gate(const float* __restrict__ x,
                                              const float* __restrict__ wg,
                                              int* __restrict__ eidx,
                                              int* __restrict__ meta,
                                              unsigned short* __restrict__ xb, int N) {
  __shared__ int lhist[4];
  int tid = threadIdx.x;
  if (tid < 4) lhist[tid] = 0;
  __syncthreads();
  int node = blockIdx.x * 16 + (tid >> 4);
  int sl = tid & 15;
  if (node < N) {
    const float* xr = x + (size_t)node * 512;
    unsigned short* xbr = xb + (size_t)node * 512;
    float l0 = 0.f, l1 = 0.f, l2 = 0.f, l3 = 0.f;
    #pragma unroll
    for (int j = 0; j < 8; ++j) {
      int q = sl + 16 * j;             // float4 index within row, 0..127
      float4 xv = *(const float4*)(xr + 4 * q);
      ushort4 ov;
      ov.x = f2bf(xv.x); ov.y = f2bf(xv.y); ov.z = f2bf(xv.z); ov.w = f2bf(xv.w);
      *(ushort4*)(xbr + 4 * q) = ov;
      float4 w0 = *(const float4*)(wg + 4 * (4 * q + 0));
      float4 w1 = *(const float4*)(wg + 4 * (4 * q + 1));
      float4 w2 = *(const float4*)(wg + 4 * (4 * q + 2));
      float4 w3 = *(const float4*)(wg + 4 * (4 * q + 3));
      l0 += xv.x * w0.x + xv.y * w1.x + xv.z * w2.x + xv.w * w3.x;
      l1 += xv.x * w0.y + xv.y * w1.y + xv.z * w2.y + xv.w * w3.y;
      l2 += xv.x * w0.z + xv.y * w1.z + xv.z * w2.z + xv.w * w3.z;
      l3 += xv.x * w0.w + xv.y * w1.w + xv.z * w2.w + xv.w * w3.w;
    }
    #pragma unroll
    for (int off = 8; off > 0; off >>= 1) {
      l0 += __shfl_xor(l0, off, 64);
      l1 += __shfl_xor(l1, off, 64);
      l2 += __shfl_xor(l2, off, 64);
      l3 += __shfl_xor(l3, off, 64);
    }
    if (sl == 0) {
      int a = 0; float best = l0;
      if (l1 > best) { best = l1; a = 1; }
      if (l2 > best) { best = l2; a = 2; }
      if (l3 > best) { best = l3; a = 3; }
      eidx[node] = a;
      atomicAdd(&lhist[a], 1);
    }
  }
  __syncthreads();
  if (tid < 4 && lhist[tid] > 0) atomicAdd(&meta[tid], lhist[tid]);
}

// meta layout: [0..3] hist, [4..8] eoff, [9..13] toff, [14..17] ecur
// M-tile = 128 rows.
__global__ void k_offs(int* meta) {
  if (threadIdx.x == 0 && blockIdx.x == 0) {
    int* hist = meta;
    int* eoff = meta + 4;
    int* toff = meta + 9;
    int* ecur = meta + 14;
    int s = 0, t = 0;
    eoff[0] = 0; toff[0] = 0;
    for (int e = 0; e < 4; ++e) {
      s += hist[e];
      eoff[e + 1] = s;
      t += (hist[e] + 127) / 128;
      toff[e + 1] = t;
      ecur[e] = eoff[e];
    }
  }
}

__global__ __launch_bounds__(256) void k_binscatter(const int* __restrict__ eidx,
                                                    int* __restrict__ meta,
                                                    int* __restrict__ perm, int N) {
  __shared__ int lhist[4];
  __shared__ int lbase[4];
  int tid = threadIdx.x;
  if (tid < 4) lhist[tid] = 0;
  __syncthreads();
  int n = blockIdx.x * 256 + tid;
  int e = 0, lrank = 0;
  bool valid = (n < N);
  if (valid) {
    e = eidx[n];
    lrank = atomicAdd(&lhist[e], 1);
  }
  __syncthreads();
  if (tid < 4) {
    int c = lhist[tid];
    lbase[tid] = (c > 0) ? atomicAdd(&meta[14 + tid], c) : 0;
  }
  __syncthreads();
  if (valid) perm[lbase[e] + lrank] = n;
}

// ---------------- pack expert weights: ewb[e][k/8][n][k%8] bf16 ----------------
__global__ __launch_bounds__(256) void k_pack(const float* __restrict__ ew,
                                              unsigned short* __restrict__ ewb) {
  int b = blockIdx.x;          // e*64 + kc
  int n = threadIdx.x;         // 0..255
  int e = b >> 6, kc = b & 63;
  const float* src = ew + ((size_t)e * 512 + (size_t)kc * 8) * 256 + n;
  unsigned short tmp[8];
  #pragma unroll
  for (int ke = 0; ke < 8; ++ke) tmp[ke] = f2bf(src[(size_t)ke * 256]);
  *(uint4*)(ewb + ((size_t)b * 256 + n) * 8) = *(const uint4*)tmp;
}

// ---------------- pack w2: w2b[k/8][n][k%8] bf16 (K=256, n=64) ----------------
__global__ __launch_bounds__(64) void k_pack2(const float* __restrict__ w2,
                                              unsigned short* __restrict__ w2b) {
  int kc = blockIdx.x;         // 0..31
  int n = threadIdx.x;         // 0..63
  const float* src = w2 + (size_t)kc * 8 * 64 + n;
  unsigned short tmp[8];
  #pragma unroll
  for (int ke = 0; ke < 8; ++ke) tmp[ke] = f2bf(src[(size_t)ke * 64]);
  *(uint4*)(w2b + ((size_t)kc * 64 + n) * 8) = *(const uint4*)tmp;
}

// ---------------- expert GEMM: bf16 MFMA 32x32x16, block tile 128x256 ----------------
__global__ __launch_bounds__(512, 2) void k_gemm1(const unsigned short* __restrict__ xb,
                                                  const unsigned short* __restrict__ ewb,
                                                  const float* __restrict__ eb,
                                                  const int* __restrict__ perm,
                                                  const int* __restrict__ meta,
                                                  unsigned short* __restrict__ h1) {
  __shared__ __align__(16) unsigned short A_lds[8192];    // [kcl 0..7][i 0..127][ke 0..7]
  __shared__ __align__(16) unsigned short B_lds[16384];   // [kcl 0..7][n 0..255][ke 0..7]
  __shared__ int sperm[128];
  const int* eoff = meta + 4;
  const int* toff = meta + 9;
  int v = blockIdx.x;
  if (v >= toff[4]) return;
  int e = 0;
  while (v >= toff[e + 1]) ++e;
  int m0 = eoff[e] + (v - toff[e]) * 128;
  int mEnd = eoff[e + 1];
  int tid = threadIdx.x;

  if (tid < 128) {
    int m = m0 + tid;
    sperm[tid] = perm[(m < mEnd) ? m : (mEnd - 1)];
  }
  __syncthreads();

  int wave = tid >> 6, lane = tid & 63;
  int wr = wave >> 2, wc = wave & 3;
  int hi = lane >> 5, lo = lane & 31;

  f32x16 acc[2][2];
  #pragma unroll
  for (int mi = 0; mi < 2; ++mi)
    #pragma unroll
    for (int ni = 0; ni < 2; ++ni)
      #pragma unroll
      for (int r = 0; r < 16; ++r) acc[mi][ni][r] = 0.f;

  const unsigned short* arow = xb + (size_t)sperm[tid & 127] * 512;
  int kclA = tid >> 7;  // 0..3 (t=0); +4 for t=1
  const uint4* ebase = (const uint4*)(ewb + (size_t)e * 64 * 2048);

  for (int k0 = 0; k0 < 512; k0 += 64) {
    uint4 a0 = *(const uint4*)(arow + k0 + kclA * 8);
    uint4 a1 = *(const uint4*)(arow + k0 + (kclA + 4) * 8);
    const uint4* bsrc = ebase + (size_t)(k0 >> 3) * 256;
    uint4 b0 = bsrc[tid];
    uint4 b1 = bsrc[512 + tid];
    uint4 b2 = bsrc[1024 + tid];
    uint4 b3 = bsrc[1536 + tid];
    __syncthreads();
    *(uint4*)&A_lds[((size_t)kclA * 128 + (tid & 127)) * 8] = a0;
    *(uint4*)&A_lds[((size_t)(kclA + 4) * 128 + (tid & 127)) * 8] = a1;
    *(uint4*)&B_lds[((size_t)0 * 512 + tid) * 8] = b0;
    *(uint4*)&B_lds[((size_t)1 * 512 + tid) * 8] = b1;
    *(uint4*)&B_lds[((size_t)2 * 512 + tid) * 8] = b2;
    *(uint4*)&B_lds[((size_t)3 * 512 + tid) * 8] = b3;
    __syncthreads();
    #pragma unroll
    for (int s = 0; s < 4; ++s) {
      int kcl = s * 2 + hi;
      bf16x8 a0f = *(const bf16x8*)&A_lds[((size_t)kcl * 128 + wr * 64 + lo) * 8];
      bf16x8 a1f = *(const bf16x8*)&A_lds[((size_t)kcl * 128 + wr * 64 + 32 + lo) * 8];
      bf16x8 b0f = *(const bf16x8*)&B_lds[((size_t)kcl * 256 + wc * 64 + lo) * 8];
      bf16x8 b1f = *(const bf16x8*)&B_lds[((size_t)kcl * 256 + wc * 64 + 32 + lo) * 8];
      acc[0][0] = __builtin_amdgcn_mfma_f32_32x32x16_bf16(a0f, b0f, acc[0][0], 0, 0, 0);
      acc[0][1] = __builtin_amdgcn_mfma_f32_32x32x16_bf16(a0f, b1f, acc[0][1], 0, 0, 0);
      acc[1][0] = __builtin_amdgcn_mfma_f32_32x32x16_bf16(a1f, b0f, acc[1][0], 0, 0, 0);
      acc[1][1] = __builtin_amdgcn_mfma_f32_32x32x16_bf16(a1f, b1f, acc[1][1], 0, 0, 0);
    }
  }

  // epilogue: bias + scatter rows as bf16. C/D: col=lane&31, row=(reg&3)+8*(reg>>2)+4*(lane>>5)
  #pragma unroll
  for (int ni = 0; ni < 2; ++ni) {
    int col = wc * 64 + ni * 32 + lo;
    float bias = eb[e * 256 + col];
    #pragma unroll
    for (int mi = 0; mi < 2; ++mi) {
      #pragma unroll
      for (int q = 0; q < 4; ++q) {
        #pragma unroll
        for (int j = 0; j < 4; ++j) {
          int r = j + 8 * q + 4 * hi;
          int lrow = wr * 64 + mi * 32 + r;
          if (m0 + lrow < mEnd) {
            h1[(size_t)sperm[lrow] * 256 + col] = f2bf(acc[mi][ni][q * 4 + j] + bias);
          }
        }
      }
    }
  }
}

// ---------------- propagate 1 (256 feat, bf16 in/out): wave per destination ----------------
// 4-way unrolled edge loop: 4 independent row-gathers in flight per wave.
__global__ __launch_bounds__(256) void k_prop1(const unsigned short* __restrict__ h1,
                                               const int* __restrict__ rowptr,
                                               const int* __restrict__ csr,
                                               const float* __restrict__ dinv,
                                               const float* __restrict__ bias1,
                                               unsigned short* __restrict__ hrelu, int N) {
  int c = blockIdx.x * 4 + (threadIdx.x >> 6);
  int lane = threadIdx.x & 63;
  if (c >= N) return;
  float dc = dinv[c];
  const ushort4* hr = (const ushort4*)h1;  // row = 64 ushort4
  ushort4 sv = hr[(size_t)c * 64 + lane];
  float sl = dc * dc;
  float ax = bf2f(sv.x) * sl, ay = bf2f(sv.y) * sl, az = bf2f(sv.z) * sl, aw = bf2f(sv.w) * sl;
  int jb = rowptr[c], je = rowptr[c + 1];
  int j = jb;
  for (; j + 3 < je; j += 4) {
    int r0 = csr[j], r1 = csr[j + 1], r2 = csr[j + 2], r3 = csr[j + 3];
    float s0 = dinv[r0] * dc, s1 = dinv[r1] * dc, s2 = dinv[r2] * dc, s3 = dinv[r3] * dc;
    ushort4 h0 = hr[(size_t)r0 * 64 + lane];
    ushort4 h1v = hr[(size_t)r1 * 64 + lane];
    ushort4 h2 = hr[(size_t)r2 * 64 + lane];
    ushort4 h3v = hr[(size_t)r3 * 64 + lane];
    ax += bf2f(h0.x) * s0; ay += bf2f(h0.y) * s0; az += bf2f(h0.z) * s0; aw += bf2f(h0.w) * s0;
    ax += bf2f(h1v.x) * s1; ay += bf2f(h1v.y) * s1; az += bf2f(h1v.z) * s1; aw += bf2f(h1v.w) * s1;
    ax += bf2f(h2.x) * s2; ay += bf2f(h2.y) * s2; az += bf2f(h2.z) * s2; aw += bf2f(h2.w) * s2;
    ax += bf2f(h3v.x) * s3; ay += bf2f(h3v.y) * s3; az += bf2f(h3v.z) * s3; aw += bf2f(h3v.w) * s3;
  }
  for (; j < je; ++j) {
    int r = csr[j];
    float s = dinv[r] * dc;
    ushort4 hv = hr[(size_t)r * 64 + lane];
    ax += bf2f(hv.x) * s; ay += bf2f(hv.y) * s; az += bf2f(hv.z) * s; aw += bf2f(hv.w) * s;
  }
  float4 b = ((const float4*)bias1)[lane];
  ushort4 ov;
  ov.x = f2bf(fmaxf(ax + b.x, 0.f));
  ov.y = f2bf(fmaxf(ay + b.y, 0.f));
  ov.z = f2bf(fmaxf(az + b.z, 0.f));
  ov.w = f2bf(fmaxf(aw + b.w, 0.f));
  ((ushort4*)hrelu)[(size_t)c * 64 + lane] = ov;
}

// ---------------- GEMM2: bf16 MFMA, [N,256]x[256,64], block tile 128x64 ----------------
__global__ __launch_bounds__(256, 2) void k_gemm2(const unsigned short* __restrict__ A,
                                                  const unsigned short* __restrict__ w2b,
                                                  unsigned short* __restrict__ h3, int N) {
  __shared__ __align__(16) unsigned short B_lds[16384];  // [kc 0..31][n 0..63][ke 0..7]
  __shared__ __align__(16) unsigned short A_lds[8192];   // [kcl 0..7][i 0..127][ke 0..7]
  int tid = threadIdx.x;
  int m0 = blockIdx.x * 128;
  #pragma unroll
  for (int it = 0; it < 8; ++it)
    *(uint4*)&B_lds[((size_t)it * 256 + tid) * 8] = ((const uint4*)w2b)[it * 256 + tid];

  int wave = tid >> 6, lane = tid & 63;
  int wr = wave >> 1, wc = wave & 1;
  int hi = lane >> 5, lo = lane & 31;

  f32x16 acc[2];
  #pragma unroll
  for (int mi = 0; mi < 2; ++mi)
    #pragma unroll
    for (int r = 0; r < 16; ++r) acc[mi][r] = 0.f;

  int i = tid & 127;
  int row = m0 + i;
  if (row >= N) row = N - 1;
  const unsigned short* arow = A + (size_t)row * 256;
  int kcl0 = tid >> 7;  // 0..1

  for (int k0 = 0; k0 < 256; k0 += 64) {
    uint4 a[4];
    #pragma unroll
    for (int t = 0; t < 4; ++t)
      a[t] = *(const uint4*)(arow + k0 + (kcl0 + 2 * t) * 8);
    __syncthreads();
    #pragma unroll
    for (int t = 0; t < 4; ++t)
      *(uint4*)&A_lds[((size_t)(kcl0 + 2 * t) * 128 + i) * 8] = a[t];
    __syncthreads();
    #pragma unroll
    for (int s = 0; s < 4; ++s) {
      int kcl = s * 2 + hi;
      bf16x8 a0f = *(const bf16x8*)&A_lds[((size_t)kcl * 128 + wr * 64 + lo) * 8];
      bf16x8 a1f = *(const bf16x8*)&A_lds[((size_t)kcl * 128 + wr * 64 + 32 + lo) * 8];
      bf16x8 bf = *(const bf16x8*)&B_lds[(((size_t)(k0 >> 3) + kcl) * 64 + wc * 32 + lo) * 8];
      acc[0] = __builtin_amdgcn_mfma_f32_32x32x16_bf16(a0f, bf, acc[0], 0, 0, 0);
      acc[1] = __builtin_amdgcn_mfma_f32_32x32x16_bf16(a1f, bf, acc[1], 0, 0, 0);
    }
  }

  int n = wc * 32 + lo;
  #pragma unroll
  for (int mi = 0; mi < 2; ++mi) {
    #pragma unroll
    for (int q = 0; q < 4; ++q) {
      #pragma unroll
      for (int j = 0; j < 4; ++j) {
        int r = j + 8 * q + 4 * hi;
        int orow = m0 + wr * 64 + mi * 32 + r;
        if (orow < N) h3[(size_t)orow * 64 + n] = f2bf(acc[mi][q * 4 + j]);
      }
    }
  }
}

// ---------------- propagate 2 (64 feat, bf16 in) + bias2 + log_softmax ----------------
// 4-way unrolled edge loop.
__global__ __launch_bounds__(256) void k_prop2(const unsigned short* __restrict__ h3,
                                               const int* __restrict__ rowptr,
                                               const int* __restrict__ csr,
                                               const float* __restrict__ dinv,
                                               const float* __restrict__ bias2,
                                               float* __restrict__ out, int N) {
  int c = blockIdx.x * 4 + (threadIdx.x >> 6);
  int f = threadIdx.x & 63;
  if (c >= N) return;
  float dc = dinv[c];
  float acc = bf2f(h3[(size_t)c * 64 + f]) * dc * dc;
  int jb = rowptr[c], je = rowptr[c + 1];
  int j = jb;
  for (; j + 3 < je; j += 4) {
    int r0 = csr[j], r1 = csr[j + 1], r2 = csr[j + 2], r3 = csr[j + 3];
    float s0 = dinv[r0] * dc, s1 = dinv[r1] * dc, s2 = dinv[r2] * dc, s3 = dinv[r3] * dc;
    float v0 = bf2f(h3[(size_t)r0 * 64 + f]);
    float v1 = bf2f(h3[(size_t)r1 * 64 + f]);
    float v2 = bf2f(h3[(size_t)r2 * 64 + f]);
    float v3 = bf2f(h3[(size_t)r3 * 64 + f]);
    acc += v0 * s0 + v1 * s1 + v2 * s2 + v3 * s3;
  }
  for (; j < je; ++j) {
    int r = csr[j];
    acc += bf2f(h3[(size_t)r * 64 + f]) * (dinv[r] * dc);
  }
  acc += bias2[f];
  float m = wave_reduce_max(acc);
  float ex = expf(acc - m);
  float s = wave_reduce_sum(ex);
  out[(size_t)c * 64 + f] = acc - m - logf(s);
}

// ---------------- launch ----------------
extern "C" void kernel_launch(void* const* d_in, const int* in_sizes, int n_in,
                              void* d_out, int out_size, void* d_ws, size_t ws_size,
                              hipStream_t stream) {
  const float* x  = (const float*)d_in[0];
  const int*   ei = (const int*)d_in[1];
  const float* wg = (const float*)d_in[2];
  const float* ew = (const float*)d_in[3];
  const float* eb = (const float*)d_in[4];
  const float* b1 = (const float*)d_in[5];
  const float* w2 = (const float*)d_in[6];
  const float* b2 = (const float*)d_in[7];
  float* out = (float*)d_out;

  int N = in_sizes[0] / 512;
  int E = in_sizes[1] / 2;
  const int* row = ei;
  const int* col = ei + E;

  char* p = (char*)d_ws;
  auto alloc = [&](size_t bytes) -> void* {
    void* r = (void*)p;
    p += (bytes + 255) & ~(size_t)255;
    return r;
  };
  int*   cnt    = (int*)alloc((size_t)N * 4);
  int*   rowptr = (int*)alloc((size_t)(N + 1) * 4);
  int*   cursor = (int*)alloc((size_t)N * 4);
  int*   bsums  = (int*)alloc(1024 * 4);
  int*   boff   = (int*)alloc(1024 * 4);
  float* dinv   = (float*)alloc((size_t)N * 4);
  int*   eidx   = (int*)alloc((size_t)N * 4);
  int*   meta   = (int*)alloc(32 * 4);
  int*   perm   = (int*)alloc((size_t)N * 4);
  int*   csr    = (int*)alloc((size_t)E * 4);
  unsigned short* h1    = (unsigned short*)alloc((size_t)N * 256 * 2);
  unsigned short* hrelu = (unsigned short*)alloc((size_t)N * 256 * 2);
  unsigned short* h3    = (unsigned short*)alloc((size_t)N * 64 * 2);
  unsigned short* xb  = (unsigned short*)alloc((size_t)N * 512 * 2);
  unsigned short* ewb = (unsigned short*)alloc((size_t)4 * 512 * 256 * 2);
  unsigned short* w2b = (unsigned short*)alloc((size_t)256 * 64 * 2);

  int nb = (N + 1023) / 1024;

  k_init<<<(N + 255) / 256, 256, 0, stream>>>(cnt, meta, N);
  k_count<<<(E + 255) / 256, 256, 0, stream>>>(col, cnt, E);
  k_scanA<<<nb, 256, 0, stream>>>(cnt, rowptr, bsums, N);
  k_scanB<<<1, 256, 0, stream>>>(bsums, boff, nb);
  k_scanC<<<(N + 255) / 256, 256, 0, stream>>>(cnt, rowptr, boff, rowptr, cursor, dinv, N, E);
  k_scatter<<<(E + 255) / 256, 256, 0, stream>>>(row, col, cursor, csr, E);
  k_pack<<<256, 256, 0, stream>>>(ew, ewb);
  k_pack2<<<32, 64, 0, stream>>>(w2, w2b);
  k_gate<<<(N + 15) / 16, 256, 0, stream>>>(x, wg, eidx, meta, xb, N);
  k_offs<<<1, 64, 0, stream>>>(meta);
  k_binscatter<<<(N + 255) / 256, 256, 0, stream>>>(eidx, meta, perm, N);
  int ntiles = (N + 127) / 128 + 4;
  k_gemm1<<<ntiles, 512, 0, stream>>>(xb, ewb, eb, perm, meta, h1);
  k_prop1<<<(N + 3) / 4, 256, 0, stream>>>(h1, rowptr, csr, dinv, b1, hrelu, N);
  k_gemm2<<<(N + 127) / 128, 256, 0, stream>>>(hrelu, w2b, h3, N);
  k_prop2<<<(N + 3) / 4, 256, 0, stream>>>(h3, rowptr, csr, dinv, b2, out, N);
}

// Round 7
// 395.059 us; speedup vs baseline: 5.9629x; 1.0771x over previous
//
#include <hip/hip_runtime.h>
#include <math.h>

typedef __bf16 bf16x8 __attribute__((ext_vector_type(8)));
typedef float f32x16 __attribute__((ext_vector_type(16)));

// ---------------- helpers ----------------
__device__ __forceinline__ float wave_reduce_sum(float v) {
  #pragma unroll
  for (int off = 32; off > 0; off >>= 1) v += __shfl_xor(v, off, 64);
  return v;
}
__device__ __forceinline__ unsigned short f2bf(float f) {
  union { float f; unsigned int u; } v; v.f = f;
  unsigned int r = (v.u + 0x7FFFu + ((v.u >> 16) & 1u)) >> 16;
  return (unsigned short)r;
}
__device__ __forceinline__ float bf2f(unsigned short u) {
  union { unsigned int u; float f; } v; v.u = ((unsigned int)u) << 16;
  return v.f;
}
// unpack 2 bf16 from one u32 (memory order: low half = even element)
__device__ __forceinline__ void bf2x(unsigned int u, float& lo, float& hi) {
  union { unsigned int u; float f; } a, b;
  a.u = u << 16; b.u = u & 0xFFFF0000u;
  lo = a.f; hi = b.f;
}

// ---------------- setup kernels ----------------
__global__ void k_init(int* cnt, int* meta, int N) {
  int i = blockIdx.x * blockDim.x + threadIdx.x;
  if (i < N) cnt[i] = 0;
  if (i < 32) meta[i] = 0;
}

__global__ void k_count(const int* __restrict__ col, int* __restrict__ cnt, int E) {
  int e = blockIdx.x * blockDim.x + threadIdx.x;
  if (e < E) atomicAdd(&cnt[col[e]], 1);
}

__global__ __launch_bounds__(256) void k_scanA(const int* __restrict__ cnt,
                                               int* __restrict__ incl,
                                               int* __restrict__ bsums, int N) {
  __shared__ int s[1024];
  int base = blockIdx.x * 1024;
  #pragma unroll
  for (int t = 0; t < 4; ++t) {
    int i = threadIdx.x + t * 256;
    int idx = base + i;
    s[i] = (idx < N) ? cnt[idx] : 0;
  }
  __syncthreads();
  for (int d = 1; d < 1024; d <<= 1) {
    int v[4];
    #pragma unroll
    for (int t = 0; t < 4; ++t) {
      int i = threadIdx.x + t * 256;
      v[t] = (i >= d) ? s[i - d] : 0;
    }
    __syncthreads();
    #pragma unroll
    for (int t = 0; t < 4; ++t) {
      int i = threadIdx.x + t * 256;
      s[i] += v[t];
    }
    __syncthreads();
  }
  #pragma unroll
  for (int t = 0; t < 4; ++t) {
    int i = threadIdx.x + t * 256;
    int idx = base + i;
    if (idx < N) incl[idx] = s[i];
  }
  if (threadIdx.x == 0) bsums[blockIdx.x] = s[1023];
}

__global__ __launch_bounds__(256) void k_scanB(const int* __restrict__ bsums,
                                               int* __restrict__ boff, int nb) {
  __shared__ int s[1024];
  #pragma unroll
  for (int t = 0; t < 4; ++t) {
    int i = threadIdx.x + t * 256;
    s[i] = (i < nb) ? bsums[i] : 0;
  }
  __syncthreads();
  for (int d = 1; d < 1024; d <<= 1) {
    int v[4];
    #pragma unroll
    for (int t = 0; t < 4; ++t) {
      int i = threadIdx.x + t * 256;
      v[t] = (i >= d) ? s[i - d] : 0;
    }
    __syncthreads();
    #pragma unroll
    for (int t = 0; t < 4; ++t) {
      int i = threadIdx.x + t * 256;
      s[i] += v[t];
    }
    __syncthreads();
  }
  #pragma unroll
  for (int t = 0; t < 4; ++t) {
    int i = threadIdx.x + t * 256;
    if (i < nb) boff[i] = (i == 0) ? 0 : s[i - 1];
  }
}

__global__ void k_scanC(const int* __restrict__ cnt, const int* __restrict__ incl,
                        const int* __restrict__ boff, int* __restrict__ rowptr,
                        int* __restrict__ cursor, float* __restrict__ dinv, int N, int E) {
  int i = blockIdx.x * blockDim.x + threadIdx.x;
  if (i < N) {
    int ex = incl[i] - cnt[i] + boff[i >> 10];
    rowptr[i] = ex;
    cursor[i] = ex;
    dinv[i] = rsqrtf((float)(cnt[i] + 1));
    if (i == 0) rowptr[N] = E;
  }
}

__global__ void k_scatter(const int* __restrict__ row, const int* __restrict__ col,
                          int* __restrict__ cursor, int* __restrict__ csr, int E) {
  int e = blockIdx.x * blockDim.x + threadIdx.x;
  if (e < E) {
    int c = col[e];
    int p = atomicAdd(&cursor[c], 1);
    csr[p] = row[e];
  }
}

// ---------------- gating + fused fp32->bf16 conversion of x ----------------
// 16 lanes per node, 16 nodes per 256-thread block.
__global__ __launch_bounds__(256) void k_gate(const float* __restrict__ x,
                                              const float* __restrict__ wg,
                                              int* __restrict__ eidx,
                                              int* __restrict__ meta,
                                              unsigned short* __restrict__ xb, int N) {
  __shared__ int lhist[4];
  int tid = threadIdx.x;
  if (tid < 4) lhist[tid] = 0;
  __syncthreads();
  int node = blockIdx.x * 16 + (tid >> 4);
  int sl = tid & 15;
  if (node < N) {
    const float* xr = x + (size_t)node * 512;
    unsigned short* xbr = xb + (size_t)node * 512;
    float l0 = 0.f, l1 = 0.f, l2 = 0.f, l3 = 0.f;
    #pragma unroll
    for (int j = 0; j < 8; ++j) {
      int q = sl + 16 * j;             // float4 index within row, 0..127
      float4 xv = *(const float4*)(xr + 4 * q);
      ushort4 ov;
      ov.x = f2bf(xv.x); ov.y = f2bf(xv.y); ov.z = f2bf(xv.z); ov.w = f2bf(xv.w);
      *(ushort4*)(xbr + 4 * q) = ov;
      float4 w0 = *(const float4*)(wg + 4 * (4 * q + 0));
      float4 w1 = *(const float4*)(wg + 4 * (4 * q + 1));
      float4 w2 = *(const float4*)(wg + 4 * (4 * q + 2));
      float4 w3 = *(const float4*)(wg + 4 * (4 * q + 3));
      l0 += xv.x * w0.x + xv.y * w1.x + xv.z * w2.x + xv.w * w3.x;
      l1 += xv.x * w0.y + xv.y * w1.y + xv.z * w2.y + xv.w * w3.y;
      l2 += xv.x * w0.z + xv.y * w1.z + xv.z * w2.z + xv.w * w3.z;
      l3 += xv.x * w0.w + xv.y * w1.w + xv.z * w2.w + xv.w * w3.w;
    }
    #pragma unroll
    for (int off = 8; off > 0; off >>= 1) {
      l0 += __shfl_xor(l0, off, 64);
      l1 += __shfl_xor(l1, off, 64);
      l2 += __shfl_xor(l2, off, 64);
      l3 += __shfl_xor(l3, off, 64);
    }
    if (sl == 0) {
      int a = 0; float best = l0;
      if (l1 > best) { best = l1; a = 1; }
      if (l2 > best) { best = l2; a = 2; }
      if (l3 > best) { best = l3; a = 3; }
      eidx[node] = a;
      atomicAdd(&lhist[a], 1);
    }
  }
  __syncthreads();
  if (tid < 4 && lhist[tid] > 0) atomicAdd(&meta[tid], lhist[tid]);
}

// meta layout: [0..3] hist, [4..8] eoff, [9..13] toff, [14..17] ecur
// M-tile = 128 rows.
__global__ void k_offs(int* meta) {
  if (threadIdx.x == 0 && blockIdx.x == 0) {
    int* hist = meta;
    int* eoff = meta + 4;
    int* toff = meta + 9;
    int* ecur = meta + 14;
    int s = 0, t = 0;
    eoff[0] = 0; toff[0] = 0;
    for (int e = 0; e < 4; ++e) {
      s += hist[e];
      eoff[e + 1] = s;
      t += (hist[e] + 127) / 128;
      toff[e + 1] = t;
      ecur[e] = eoff[e];
    }
  }
}

__global__ __launch_bounds__(256) void k_binscatter(const int* __restrict__ eidx,
                                                    int* __restrict__ meta,
                                                    int* __restrict__ perm, int N) {
  __shared__ int lhist[4];
  __shared__ int lbase[4];
  int tid = threadIdx.x;
  if (tid < 4) lhist[tid] = 0;
  __syncthreads();
  int n = blockIdx.x * 256 + tid;
  int e = 0, lrank = 0;
  bool valid = (n < N);
  if (valid) {
    e = eidx[n];
    lrank = atomicAdd(&lhist[e], 1);
  }
  __syncthreads();
  if (tid < 4) {
    int c = lhist[tid];
    lbase[tid] = (c > 0) ? atomicAdd(&meta[14 + tid], c) : 0;
  }
  __syncthreads();
  if (valid) perm[lbase[e] + lrank] = n;
}

// ---------------- pack expert weights: ewb[e][k/8][n][k%8] bf16 ----------------
__global__ __launch_bounds__(256) void k_pack(const float* __restrict__ ew,
                                              unsigned short* __restrict__ ewb) {
  int b = blockIdx.x;          // e*64 + kc
  int n = threadIdx.x;         // 0..255
  int e = b >> 6, kc = b & 63;
  const float* src = ew + ((size_t)e * 512 + (size_t)kc * 8) * 256 + n;
  unsigned short tmp[8];
  #pragma unroll
  for (int ke = 0; ke < 8; ++ke) tmp[ke] = f2bf(src[(size_t)ke * 256]);
  *(uint4*)(ewb + ((size_t)b * 256 + n) * 8) = *(const uint4*)tmp;
}

// ---------------- pack w2: w2b[k/8][n][k%8] bf16 (K=256, n=64) ----------------
__global__ __launch_bounds__(64) void k_pack2(const float* __restrict__ w2,
                                              unsigned short* __restrict__ w2b) {
  int kc = blockIdx.x;         // 0..31
  int n = threadIdx.x;         // 0..63
  const float* src = w2 + (size_t)kc * 8 * 64 + n;
  unsigned short tmp[8];
  #pragma unroll
  for (int ke = 0; ke < 8; ++ke) tmp[ke] = f2bf(src[(size_t)ke * 64]);
  *(uint4*)(w2b + ((size_t)kc * 64 + n) * 8) = *(const uint4*)tmp;
}

// ---------------- expert GEMM: bf16 MFMA 32x32x16, block tile 128x256 ----------------
__global__ __launch_bounds__(512, 2) void k_gemm1(const unsigned short* __restrict__ xb,
                                                  const unsigned short* __restrict__ ewb,
                                                  const float* __restrict__ eb,
                                                  const int* __restrict__ perm,
                                                  const int* __restrict__ meta,
                                                  unsigned short* __restrict__ h1) {
  __shared__ __align__(16) unsigned short A_lds[8192];    // [kcl 0..7][i 0..127][ke 0..7]
  __shared__ __align__(16) unsigned short B_lds[16384];   // [kcl 0..7][n 0..255][ke 0..7]
  __shared__ int sperm[128];
  const int* eoff = meta + 4;
  const int* toff = meta + 9;
  int v = blockIdx.x;
  if (v >= toff[4]) return;
  int e = 0;
  while (v >= toff[e + 1]) ++e;
  int m0 = eoff[e] + (v - toff[e]) * 128;
  int mEnd = eoff[e + 1];
  int tid = threadIdx.x;

  if (tid < 128) {
    int m = m0 + tid;
    sperm[tid] = perm[(m < mEnd) ? m : (mEnd - 1)];
  }
  __syncthreads();

  int wave = tid >> 6, lane = tid & 63;
  int wr = wave >> 2, wc = wave & 3;
  int hi = lane >> 5, lo = lane & 31;

  f32x16 acc[2][2];
  #pragma unroll
  for (int mi = 0; mi < 2; ++mi)
    #pragma unroll
    for (int ni = 0; ni < 2; ++ni)
      #pragma unroll
      for (int r = 0; r < 16; ++r) acc[mi][ni][r] = 0.f;

  const unsigned short* arow = xb + (size_t)sperm[tid & 127] * 512;
  int kclA = tid >> 7;  // 0..3 (t=0); +4 for t=1
  const uint4* ebase = (const uint4*)(ewb + (size_t)e * 64 * 2048);

  for (int k0 = 0; k0 < 512; k0 += 64) {
    uint4 a0 = *(const uint4*)(arow + k0 + kclA * 8);
    uint4 a1 = *(const uint4*)(arow + k0 + (kclA + 4) * 8);
    const uint4* bsrc = ebase + (size_t)(k0 >> 3) * 256;
    uint4 b0 = bsrc[tid];
    uint4 b1 = bsrc[512 + tid];
    uint4 b2 = bsrc[1024 + tid];
    uint4 b3 = bsrc[1536 + tid];
    __syncthreads();
    *(uint4*)&A_lds[((size_t)kclA * 128 + (tid & 127)) * 8] = a0;
    *(uint4*)&A_lds[((size_t)(kclA + 4) * 128 + (tid & 127)) * 8] = a1;
    *(uint4*)&B_lds[((size_t)0 * 512 + tid) * 8] = b0;
    *(uint4*)&B_lds[((size_t)1 * 512 + tid) * 8] = b1;
    *(uint4*)&B_lds[((size_t)2 * 512 + tid) * 8] = b2;
    *(uint4*)&B_lds[((size_t)3 * 512 + tid) * 8] = b3;
    __syncthreads();
    #pragma unroll
    for (int s = 0; s < 4; ++s) {
      int kcl = s * 2 + hi;
      bf16x8 a0f = *(const bf16x8*)&A_lds[((size_t)kcl * 128 + wr * 64 + lo) * 8];
      bf16x8 a1f = *(const bf16x8*)&A_lds[((size_t)kcl * 128 + wr * 64 + 32 + lo) * 8];
      bf16x8 b0f = *(const bf16x8*)&B_lds[((size_t)kcl * 256 + wc * 64 + lo) * 8];
      bf16x8 b1f = *(const bf16x8*)&B_lds[((size_t)kcl * 256 + wc * 64 + 32 + lo) * 8];
      acc[0][0] = __builtin_amdgcn_mfma_f32_32x32x16_bf16(a0f, b0f, acc[0][0], 0, 0, 0);
      acc[0][1] = __builtin_amdgcn_mfma_f32_32x32x16_bf16(a0f, b1f, acc[0][1], 0, 0, 0);
      acc[1][0] = __builtin_amdgcn_mfma_f32_32x32x16_bf16(a1f, b0f, acc[1][0], 0, 0, 0);
      acc[1][1] = __builtin_amdgcn_mfma_f32_32x32x16_bf16(a1f, b1f, acc[1][1], 0, 0, 0);
    }
  }

  // epilogue: bias + scatter rows as bf16. C/D: col=lane&31, row=(reg&3)+8*(reg>>2)+4*(lane>>5)
  #pragma unroll
  for (int ni = 0; ni < 2; ++ni) {
    int col = wc * 64 + ni * 32 + lo;
    float bias = eb[e * 256 + col];
    #pragma unroll
    for (int mi = 0; mi < 2; ++mi) {
      #pragma unroll
      for (int q = 0; q < 4; ++q) {
        #pragma unroll
        for (int j = 0; j < 4; ++j) {
          int r = j + 8 * q + 4 * hi;
          int lrow = wr * 64 + mi * 32 + r;
          if (m0 + lrow < mEnd) {
            h1[(size_t)sperm[lrow] * 256 + col] = f2bf(acc[mi][ni][q * 4 + j] + bias);
          }
        }
      }
    }
  }
}

// ---------------- propagate 1 (256 feat, bf16): 32 lanes/row, 8 rows/block ----------------
__global__ __launch_bounds__(256) void k_prop1(const unsigned short* __restrict__ h1,
                                               const int* __restrict__ rowptr,
                                               const int* __restrict__ csr,
                                               const float* __restrict__ dinv,
                                               const float* __restrict__ bias1,
                                               unsigned short* __restrict__ hrelu, int N) {
  int tid = threadIdx.x;
  int c = blockIdx.x * 8 + (tid >> 5);
  int l = tid & 31;                        // 8 features per lane
  if (c >= N) return;
  float dc = dinv[c];
  const uint4* hr = (const uint4*)h1;      // row = 32 uint4
  uint4 sv = hr[(size_t)c * 32 + l];
  float slf = dc * dc;
  float a0, a1, a2, a3, a4, a5, a6, a7;
  {
    float lo, hi;
    bf2x(sv.x, lo, hi); a0 = lo * slf; a1 = hi * slf;
    bf2x(sv.y, lo, hi); a2 = lo * slf; a3 = hi * slf;
    bf2x(sv.z, lo, hi); a4 = lo * slf; a5 = hi * slf;
    bf2x(sv.w, lo, hi); a6 = lo * slf; a7 = hi * slf;
  }
  int jb = rowptr[c], je = rowptr[c + 1];
  int j = jb;
  #define ACC8(v, s) { float lo, hi; \
    bf2x((v).x, lo, hi); a0 += lo * (s); a1 += hi * (s); \
    bf2x((v).y, lo, hi); a2 += lo * (s); a3 += hi * (s); \
    bf2x((v).z, lo, hi); a4 += lo * (s); a5 += hi * (s); \
    bf2x((v).w, lo, hi); a6 += lo * (s); a7 += hi * (s); }
  for (; j + 3 < je; j += 4) {
    int r0 = csr[j], r1 = csr[j + 1], r2 = csr[j + 2], r3 = csr[j + 3];
    float s0 = dinv[r0] * dc, s1 = dinv[r1] * dc, s2 = dinv[r2] * dc, s3 = dinv[r3] * dc;
    uint4 v0 = hr[(size_t)r0 * 32 + l];
    uint4 v1 = hr[(size_t)r1 * 32 + l];
    uint4 v2 = hr[(size_t)r2 * 32 + l];
    uint4 v3 = hr[(size_t)r3 * 32 + l];
    ACC8(v0, s0); ACC8(v1, s1); ACC8(v2, s2); ACC8(v3, s3);
  }
  for (; j < je; ++j) {
    int r = csr[j];
    float s = dinv[r] * dc;
    uint4 v = hr[(size_t)r * 32 + l];
    ACC8(v, s);
  }
  #undef ACC8
  float4 b01 = *(const float4*)(bias1 + l * 8);
  float4 b23 = *(const float4*)(bias1 + l * 8 + 4);
  a0 = fmaxf(a0 + b01.x, 0.f); a1 = fmaxf(a1 + b01.y, 0.f);
  a2 = fmaxf(a2 + b01.z, 0.f); a3 = fmaxf(a3 + b01.w, 0.f);
  a4 = fmaxf(a4 + b23.x, 0.f); a5 = fmaxf(a5 + b23.y, 0.f);
  a6 = fmaxf(a6 + b23.z, 0.f); a7 = fmaxf(a7 + b23.w, 0.f);
  uint4 ov;
  ov.x = ((unsigned int)f2bf(a1) << 16) | f2bf(a0);
  ov.y = ((unsigned int)f2bf(a3) << 16) | f2bf(a2);
  ov.z = ((unsigned int)f2bf(a5) << 16) | f2bf(a4);
  ov.w = ((unsigned int)f2bf(a7) << 16) | f2bf(a6);
  ((uint4*)hrelu)[(size_t)c * 32 + l] = ov;
}

// ---------------- GEMM2: bf16 MFMA, [N,256]x[256,64], block tile 128x64 ----------------
__global__ __launch_bounds__(256, 2) void k_gemm2(const unsigned short* __restrict__ A,
                                                  const unsigned short* __restrict__ w2b,
                                                  unsigned short* __restrict__ h3, int N) {
  __shared__ __align__(16) unsigned short B_lds[16384];  // [kc 0..31][n 0..63][ke 0..7]
  __shared__ __align__(16) unsigned short A_lds[8192];   // [kcl 0..7][i 0..127][ke 0..7]
  int tid = threadIdx.x;
  int m0 = blockIdx.x * 128;
  #pragma unroll
  for (int it = 0; it < 8; ++it)
    *(uint4*)&B_lds[((size_t)it * 256 + tid) * 8] = ((const uint4*)w2b)[it * 256 + tid];

  int wave = tid >> 6, lane = tid & 63;
  int wr = wave >> 1, wc = wave & 1;
  int hi = lane >> 5, lo = lane & 31;

  f32x16 acc[2];
  #pragma unroll
  for (int mi = 0; mi < 2; ++mi)
    #pragma unroll
    for (int r = 0; r < 16; ++r) acc[mi][r] = 0.f;

  int i = tid & 127;
  int row = m0 + i;
  if (row >= N) row = N - 1;
  const unsigned short* arow = A + (size_t)row * 256;
  int kcl0 = tid >> 7;  // 0..1

  for (int k0 = 0; k0 < 256; k0 += 64) {
    uint4 a[4];
    #pragma unroll
    for (int t = 0; t < 4; ++t)
      a[t] = *(const uint4*)(arow + k0 + (kcl0 + 2 * t) * 8);
    __syncthreads();
    #pragma unroll
    for (int t = 0; t < 4; ++t)
      *(uint4*)&A_lds[((size_t)(kcl0 + 2 * t) * 128 + i) * 8] = a[t];
    __syncthreads();
    #pragma unroll
    for (int s = 0; s < 4; ++s) {
      int kcl = s * 2 + hi;
      bf16x8 a0f = *(const bf16x8*)&A_lds[((size_t)kcl * 128 + wr * 64 + lo) * 8];
      bf16x8 a1f = *(const bf16x8*)&A_lds[((size_t)kcl * 128 + wr * 64 + 32 + lo) * 8];
      bf16x8 bf = *(const bf16x8*)&B_lds[(((size_t)(k0 >> 3) + kcl) * 64 + wc * 32 + lo) * 8];
      acc[0] = __builtin_amdgcn_mfma_f32_32x32x16_bf16(a0f, bf, acc[0], 0, 0, 0);
      acc[1] = __builtin_amdgcn_mfma_f32_32x32x16_bf16(a1f, bf, acc[1], 0, 0, 0);
    }
  }

  int n = wc * 32 + lo;
  #pragma unroll
  for (int mi = 0; mi < 2; ++mi) {
    #pragma unroll
    for (int q = 0; q < 4; ++q) {
      #pragma unroll
      for (int j = 0; j < 4; ++j) {
        int r = j + 8 * q + 4 * hi;
        int orow = m0 + wr * 64 + mi * 32 + r;
        if (orow < N) h3[(size_t)orow * 64 + n] = f2bf(acc[mi][q * 4 + j]);
      }
    }
  }
}

// ---------------- propagate 2 (64 feat, bf16): 8 lanes/row, 32 rows/block ----------------
__global__ __launch_bounds__(256) void k_prop2(const unsigned short* __restrict__ h3,
                                               const int* __restrict__ rowptr,
                                               const int* __restrict__ csr,
                                               const float* __restrict__ dinv,
                                               const float* __restrict__ bias2,
                                               float* __restrict__ out, int N) {
  int tid = threadIdx.x;
  int c = blockIdx.x * 32 + (tid >> 3);
  int l = tid & 7;                         // 8 features per lane
  if (c >= N) return;
  float dc = dinv[c];
  const uint4* hr = (const uint4*)h3;      // row = 8 uint4
  uint4 sv = hr[(size_t)c * 8 + l];
  float slf = dc * dc;
  float a0, a1, a2, a3, a4, a5, a6, a7;
  {
    float lo, hi;
    bf2x(sv.x, lo, hi); a0 = lo * slf; a1 = hi * slf;
    bf2x(sv.y, lo, hi); a2 = lo * slf; a3 = hi * slf;
    bf2x(sv.z, lo, hi); a4 = lo * slf; a5 = hi * slf;
    bf2x(sv.w, lo, hi); a6 = lo * slf; a7 = hi * slf;
  }
  int jb = rowptr[c], je = rowptr[c + 1];
  int j = jb;
  #define ACC8(v, s) { float lo, hi; \
    bf2x((v).x, lo, hi); a0 += lo * (s); a1 += hi * (s); \
    bf2x((v).y, lo, hi); a2 += lo * (s); a3 += hi * (s); \
    bf2x((v).z, lo, hi); a4 += lo * (s); a5 += hi * (s); \
    bf2x((v).w, lo, hi); a6 += lo * (s); a7 += hi * (s); }
  for (; j + 3 < je; j += 4) {
    int r0 = csr[j], r1 = csr[j + 1], r2 = csr[j + 2], r3 = csr[j + 3];
    float s0 = dinv[r0] * dc, s1 = dinv[r1] * dc, s2 = dinv[r2] * dc, s3 = dinv[r3] * dc;
    uint4 v0 = hr[(size_t)r0 * 8 + l];
    uint4 v1 = hr[(size_t)r1 * 8 + l];
    uint4 v2 = hr[(size_t)r2 * 8 + l];
    uint4 v3 = hr[(size_t)r3 * 8 + l];
    ACC8(v0, s0); ACC8(v1, s1); ACC8(v2, s2); ACC8(v3, s3);
  }
  for (; j < je; ++j) {
    int r = csr[j];
    float s = dinv[r] * dc;
    uint4 v = hr[(size_t)r * 8 + l];
    ACC8(v, s);
  }
  #undef ACC8
  float4 b01 = *(const float4*)(bias2 + l * 8);
  float4 b23 = *(const float4*)(bias2 + l * 8 + 4);
  a0 += b01.x; a1 += b01.y; a2 += b01.z; a3 += b01.w;
  a4 += b23.x; a5 += b23.y; a6 += b23.z; a7 += b23.w;
  // log_softmax over 64 features spread across 8 lanes x 8 values
  float m = fmaxf(fmaxf(fmaxf(a0, a1), fmaxf(a2, a3)), fmaxf(fmaxf(a4, a5), fmaxf(a6, a7)));
  #pragma unroll
  for (int off = 4; off > 0; off >>= 1) m = fmaxf(m, __shfl_xor(m, off, 64));
  float s = expf(a0 - m) + expf(a1 - m) + expf(a2 - m) + expf(a3 - m)
          + expf(a4 - m) + expf(a5 - m) + expf(a6 - m) + expf(a7 - m);
  #pragma unroll
  for (int off = 4; off > 0; off >>= 1) s += __shfl_xor(s, off, 64);
  float ls = m + logf(s);
  float* orow = out + (size_t)c * 64 + l * 8;
  float4 o0 = make_float4(a0 - ls, a1 - ls, a2 - ls, a3 - ls);
  float4 o1 = make_float4(a4 - ls, a5 - ls, a6 - ls, a7 - ls);
  *(float4*)orow = o0;
  *(float4*)(orow + 4) = o1;
}

// ---------------- launch ----------------
extern "C" void kernel_launch(void* const* d_in, const int* in_sizes, int n_in,
                              void* d_out, int out_size, void* d_ws, size_t ws_size,
                              hipStream_t stream) {
  const float* x  = (const float*)d_in[0];
  const int*   ei = (const int*)d_in[1];
  const float* wg = (const float*)d_in[2];
  const float* ew = (const float*)d_in[3];
  const float* eb = (const float*)d_in[4];
  const float* b1 = (const float*)d_in[5];
  const float* w2 = (const float*)d_in[6];
  const float* b2 = (const float*)d_in[7];
  float* out = (float*)d_out;

  int N = in_sizes[0] / 512;
  int E = in_sizes[1] / 2;
  const int* row = ei;
  const int* col = ei + E;

  char* p = (char*)d_ws;
  auto alloc = [&](size_t bytes) -> void* {
    void* r = (void*)p;
    p += (bytes + 255) & ~(size_t)255;
    return r;
  };
  int*   cnt    = (int*)alloc((size_t)N * 4);
  int*   rowptr = (int*)alloc((size_t)(N + 1) * 4);
  int*   cursor = (int*)alloc((size_t)N * 4);
  int*   bsums  = (int*)alloc(1024 * 4);
  int*   boff   = (int*)alloc(1024 * 4);
  float* dinv   = (float*)alloc((size_t)N * 4);
  int*   eidx   = (int*)alloc((size_t)N * 4);
  int*   meta   = (int*)alloc(32 * 4);
  int*   perm   = (int*)alloc((size_t)N * 4);
  int*   csr    = (int*)alloc((size_t)E * 4);
  unsigned short* h1    = (unsigned short*)alloc((size_t)N * 256 * 2);
  unsigned short* hrelu = (unsigned short*)alloc((size_t)N * 256 * 2);
  unsigned short* h3    = (unsigned short*)alloc((size_t)N * 64 * 2);
  unsigned short* xb  = (unsigned short*)alloc((size_t)N * 512 * 2);
  unsigned short* ewb = (unsigned short*)alloc((size_t)4 * 512 * 256 * 2);
  unsigned short* w2b = (unsigned short*)alloc((size_t)256 * 64 * 2);

  int nb = (N + 1023) / 1024;

  k_init<<<(N + 255) / 256, 256, 0, stream>>>(cnt, meta, N);
  k_count<<<(E + 255) / 256, 256, 0, stream>>>(col, cnt, E);
  k_scanA<<<nb, 256, 0, stream>>>(cnt, rowptr, bsums, N);
  k_scanB<<<1, 256, 0, stream>>>(bsums, boff, nb);
  k_scanC<<<(N + 255) / 256, 256, 0, stream>>>(cnt, rowptr, boff, rowptr, cursor, dinv, N, E);
  k_scatter<<<(E + 255) / 256, 256, 0, stream>>>(row, col, cursor, csr, E);
  k_pack<<<256, 256, 0, stream>>>(ew, ewb);
  k_pack2<<<32, 64, 0, stream>>>(w2, w2b);
  k_gate<<<(N + 15) / 16, 256, 0, stream>>>(x, wg, eidx, meta, xb, N);
  k_offs<<<1, 64, 0, stream>>>(meta);
  k_binscatter<<<(N + 255) / 256, 256, 0, stream>>>(eidx, meta, perm, N);
  int ntiles = (N + 127) / 128 + 4;
  k_gemm1<<<ntiles, 512, 0, stream>>>(xb, ewb, eb, perm, meta, h1);
  k_prop1<<<(N + 7) / 8, 256, 0, stream>>>(h1, rowptr, csr, dinv, b1, hrelu, N);
  k_gemm2<<<(N + 127) / 128, 256, 0, stream>>>(hrelu, w2b, h3, N);
  k_prop2<<<(N + 31) / 32, 256, 0, stream>>>(h3, rowptr, csr, dinv, b2, out, N);
}